// Round 9
// baseline (222.323 us; speedup 1.0000x reference)
//
#include <hip/hip_runtime.h>
#include <hip/hip_bf16.h>
#include <math.h>

#define NB 2
#define SS 2048
#define HH 1024
#define NHEAD 16
#define HDIM 64
#define NTOK (NB * SS)  // 4096

#define QSCALE 0.18033688011112042f   // 0.125 * log2(e)
#define MSCALE (-14426.950408889634f) // -10000 * log2(e)

typedef __attribute__((ext_vector_type(8))) short short8;
typedef __attribute__((ext_vector_type(4))) float f32x4;
typedef __attribute__((ext_vector_type(16))) float f32x16;

// byte-offset swizzle within a 128B LDS row: XOR 16B-chunk index with (row&7)
#define SWZ16(row, boff) ((boff) ^ (((row) & 7) << 4))

// f32 -> bf16 round-to-nearest-even
__device__ __forceinline__ unsigned short f2b(float x) {
    union { float f; unsigned int u; } v; v.f = x;
    unsigned int u = v.u + 0x7fff + ((v.u >> 16) & 1);
    return (unsigned short)(u >> 16);
}

// pack two f32 -> one dword of 2 bf16 via HW instruction (T12)
__device__ __forceinline__ unsigned pk2a(float lo, float hi) {
    unsigned r;
    asm("v_cvt_pk_bf16_f32 %0, %1, %2" : "=v"(r) : "v"(lo), "v"(hi));
    return r;
}

__device__ __forceinline__ float exp2fast(float x) {
#if __has_builtin(__builtin_amdgcn_exp2f)
    return __builtin_amdgcn_exp2f(x);
#else
    return exp2f(x);
#endif
}

// async global->LDS, 16B per lane
__device__ __forceinline__ void gl16(const void* g, void* l) {
    __builtin_amdgcn_global_load_lds(
        (const __attribute__((address_space(1))) void*)g,
        (__attribute__((address_space(3))) void*)l, 16, 0, 0);
}

// ---------------------------------------------------------------------------
// hs f32 -> bf16 row-major
// ---------------------------------------------------------------------------
__global__ __launch_bounds__(256) void cvt_hs(
    const float* __restrict__ X, unsigned short* __restrict__ Y)
{
    const size_t i = ((size_t)blockIdx.x * 256 + threadIdx.x) * 8;
    float4 v0 = *(const float4*)(X + i);
    float4 v1 = *(const float4*)(X + i + 4);
    short8 o;
    o[0] = f2b(v0.x); o[1] = f2b(v0.y); o[2] = f2b(v0.z); o[3] = f2b(v0.w);
    o[4] = f2b(v1.x); o[5] = f2b(v1.y); o[6] = f2b(v1.z); o[7] = f2b(v1.w);
    *(short8*)(Y + i) = o;
}

// mask -> premultiplied log2-domain bias
__global__ __launch_bounds__(256) void prep_mask(
    const float* __restrict__ m, float* __restrict__ o)
{
    const int i = blockIdx.x * 256 + threadIdx.x;
    o[i] = m[i] * MSCALE;
}

// ---------------------------------------------------------------------------
// W f32 [K][N] -> Wt bf16 [N][K]  (4 weights via blockIdx.z)
// ---------------------------------------------------------------------------
__global__ __launch_bounds__(256) void transpose_w(
    const float* __restrict__ W0, const float* __restrict__ W1,
    const float* __restrict__ W2, const float* __restrict__ W3,
    unsigned short* __restrict__ Wt)
{
    const float* W = blockIdx.z == 0 ? W0 : blockIdx.z == 1 ? W1 :
                     blockIdx.z == 2 ? W2 : W3;
    unsigned short* dst = Wt + (size_t)blockIdx.z * HH * HH;
    __shared__ unsigned short T[64][72];
    const int tid = threadIdx.x;
    const int n0 = blockIdx.x * 64, k0 = blockIdx.y * 64;
    {
        const int r = tid >> 2, c4 = (tid & 3) * 16;
        const float* src = W + (size_t)(k0 + r) * HH + n0 + c4;
#pragma unroll
        for (int j = 0; j < 16; j += 4) {
            float4 v = *(const float4*)(src + j);
            T[c4 + j + 0][r] = f2b(v.x); T[c4 + j + 1][r] = f2b(v.y);
            T[c4 + j + 2][r] = f2b(v.z); T[c4 + j + 3][r] = f2b(v.w);
        }
    }
    __syncthreads();
    {
        const int n = tid >> 2, sc = (tid & 3) * 2;
#pragma unroll
        for (int u = 0; u < 2; ++u) {
            short8 v = *(const short8*)&T[n][(sc + u) * 8];
            *(short8*)(dst + (size_t)(n0 + n) * HH + k0 + (sc + u) * 8) = v;
        }
    }
}

// ---------------------------------------------------------------------------
// bf16 MFMA GEMM. OUT=0: fused QKV (N=3072): Q scaled by QSCALE, all three
// written bf16 head-major [bh][si][d]. OUT=2: f32 row-major.
// ---------------------------------------------------------------------------
template<int OUT>
__global__ __launch_bounds__(256) void gemm_bf16(
    const unsigned short* __restrict__ A, const unsigned short* __restrict__ Bt,
    const float* __restrict__ b0, const float* __restrict__ b1,
    const float* __restrict__ b2, void* __restrict__ Cout)
{
    __shared__ __align__(16) unsigned short As[2][128 * 64];
    __shared__ __align__(16) unsigned short Bs[2][128 * 64];

    const int tid = threadIdx.x;
    const int w  = tid >> 6;
    const int l  = tid & 63;
    const int g  = l >> 4, c = l & 15;
    const int wr = w >> 1, wc = w & 1;
    const int m0 = blockIdx.y * 128, n0 = blockIdx.x * 128;

    const int dr = l >> 3;
    const int gc = (l & 7) ^ dr;

    const unsigned short* aBase = A  + (size_t)(m0 + w * 32 + dr) * HH + gc * 8;
    const unsigned short* bBase = Bt + (size_t)(n0 + w * 32 + dr) * HH + gc * 8;

    f32x4 acc[4][4];
#pragma unroll
    for (int mi = 0; mi < 4; ++mi)
#pragma unroll
        for (int ni = 0; ni < 4; ++ni)
            acc[mi][ni] = (f32x4){0.f, 0.f, 0.f, 0.f};

    const int swz = (c & 7) * 8;

#define STAGE(kt_, bb) {                                                      \
    const int koff = (kt_) * 64;                                              \
    _Pragma("unroll")                                                         \
    for (int i_ = 0; i_ < 4; ++i_) {                                          \
        gl16(aBase + koff + (size_t)i_ * 8 * HH, (void*)&As[bb][(w*4+i_)*512]); \
        gl16(bBase + koff + (size_t)i_ * 8 * HH, (void*)&Bs[bb][(w*4+i_)*512]); \
    } }

    STAGE(0, 0);
    __syncthreads();
    int cur = 0;

    for (int kt = 0; kt < 16; ++kt) {
        if (kt < 15) STAGE(kt + 1, cur ^ 1);

        short8 af[2][4], bf[2][4];
#pragma unroll
        for (int ks = 0; ks < 2; ++ks) {
            const int kb = ks * 32;
#pragma unroll
            for (int mi = 0; mi < 4; ++mi) {
                const int row = wr * 64 + mi * 16 + c;
                af[ks][mi] = *(const short8*)&As[cur][row * 64 + ((kb + g * 8) ^ swz)];
            }
#pragma unroll
            for (int ni = 0; ni < 4; ++ni) {
                const int row = wc * 64 + ni * 16 + c;
                bf[ks][ni] = *(const short8*)&Bs[cur][row * 64 + ((kb + g * 8) ^ swz)];
            }
        }
        __builtin_amdgcn_s_setprio(1);
#pragma unroll
        for (int ks = 0; ks < 2; ++ks)
#pragma unroll
            for (int mi = 0; mi < 4; ++mi)
#pragma unroll
                for (int ni = 0; ni < 4; ++ni)
                    acc[mi][ni] = __builtin_amdgcn_mfma_f32_16x16x32_bf16(
                        af[ks][mi], bf[ks][ni], acc[mi][ni], 0, 0, 0);
        __builtin_amdgcn_s_setprio(0);

        __syncthreads();
        cur ^= 1;
    }
#undef STAGE

    if (OUT == 0) {
        const int which = n0 >> 10;   // block-uniform: 0=Q, 1=K, 2=V
        const float* bp = which == 0 ? b0 : which == 1 ? b1 : b2;
        const float scl = which == 0 ? QSCALE : 1.0f;
        unsigned short* dst = (unsigned short*)Cout + (size_t)which * NTOK * HH;
#pragma unroll
        for (int ni = 0; ni < 4; ++ni) {
            const int nl = (n0 + wc * 64 + ni * 16 + c) & 1023;
            const int h = nl >> 6, d = nl & 63;
            const float bv = bp[nl];
#pragma unroll
            for (int mi = 0; mi < 4; ++mi) {
                const int mBase = m0 + wr * 64 + mi * 16 + g * 4;
#pragma unroll
                for (int j = 0; j < 4; ++j) {
                    const int m = mBase + j;
                    const int b = m >> 11, si = m & 2047;
                    dst[(((size_t)(b * 16 + h)) * SS + si) * 64 + d] =
                        f2b((acc[mi][ni][j] + bv) * scl);
                }
            }
        }
    } else {
#pragma unroll
        for (int ni = 0; ni < 4; ++ni) {
            const int n = n0 + wc * 64 + ni * 16 + c;
            const float bv = b0[n];
#pragma unroll
            for (int mi = 0; mi < 4; ++mi) {
                const int mBase = m0 + wr * 64 + mi * 16 + g * 4;
#pragma unroll
                for (int j = 0; j < 4; ++j)
                    ((float*)Cout)[(size_t)(mBase + j) * HH + n] =
                        acc[mi][ni][j] + bv;
            }
        }
    }
}

// ---------------------------------------------------------------------------
// V head-major [bh][s][64] -> Vt [bh][64][s]
// ---------------------------------------------------------------------------
__global__ __launch_bounds__(256) void vtrans(
    const unsigned short* __restrict__ Vh, unsigned short* __restrict__ Vt)
{
    __shared__ unsigned short T[64][72];
    const int tid = threadIdx.x;
    const int bh = blockIdx.y;
    const int s0 = blockIdx.x * 64;
    {
        const int r = tid >> 2, dc = (tid & 3) * 16;
        const unsigned short* src = Vh + ((size_t)bh * SS + s0 + r) * 64 + dc;
        short8 v0 = *(const short8*)src;
        short8 v1 = *(const short8*)(src + 8);
#pragma unroll
        for (int j = 0; j < 8; ++j) {
            T[dc + j][r]     = (unsigned short)v0[j];
            T[dc + 8 + j][r] = (unsigned short)v1[j];
        }
    }
    __syncthreads();
    {
        const int d = tid >> 2, sc = (tid & 3) * 2;
#pragma unroll
        for (int u = 0; u < 2; ++u) {
            short8 v = *(const short8*)&T[d][(sc + u) * 8];
            *(short8*)(Vt + ((size_t)bh * 64 + d) * SS + s0 + (sc + u) * 8) = v;
        }
    }
}

// ---------------------------------------------------------------------------
// Flash attention, swapped-QK^T 32x32x16, no-max log2 softmax (exact).
// NO LDS, NO BARRIERS: K/V fragments read directly from global (L1/L2-hit;
// K and V per head are L2-resident with XCD swizzle). K fragments
// software-pipelined one tile ahead (kfA/kfB, unroll-2, static indexing).
// 4 independent waves x 32 q = 128 q/block, grid 512 (2 blocks/CU).
// ---------------------------------------------------------------------------
__global__ __launch_bounds__(256) void attn_mfma(
    const unsigned short* __restrict__ Qb, const unsigned short* __restrict__ Kb,
    const unsigned short* __restrict__ Vtb, const float* __restrict__ mbuf,
    unsigned short* __restrict__ ctx)
{
    __shared__ float Sc[4][32];   // tiny: per-wave l broadcast only

    // XCD swizzle: 512 blocks, 8 XCDs -> 64-block contiguous chunks
    const int wg  = blockIdx.x;
    const int swg = (wg & 7) * 64 + (wg >> 3);
    const int qx  = swg & 15;       // 16 q-blocks of 128
    const int bh  = swg >> 4;       // 32

    const int tid = threadIdx.x;
    const int l   = tid & 63;
    const int wq  = tid >> 6;       // wave 0..3 (independent)
    const int hi  = l >> 5;
    const int c   = l & 31;
    const int b   = bh >> 4, h = bh & 15;
    const int q0  = qx * 128 + wq * 32;

    const unsigned short* Qp = Qb + (size_t)bh * SS * 64;
    // lane-fragment base pointers (hi*8 folded in)
    const unsigned short* Kl = Kb  + (size_t)bh * SS * 64 + (size_t)c * 64 + hi * 8;
    const unsigned short* Vl = Vtb + (size_t)bh * 64 * SS + (size_t)c * SS + hi * 8;
    const float* maskp = mbuf + (size_t)b * SS;

    // Q B-fragments (pre-scaled by QSCALE in GEMM)
    short8 qf[4];
    {
        const unsigned short* qrow = Qp + (size_t)(q0 + c) * 64 + hi * 8;
#pragma unroll
        for (int s = 0; s < 4; ++s) qf[s] = *(const short8*)(qrow + s * 16);
    }

    f32x16 oacc[2];
#pragma unroll
    for (int dt = 0; dt < 2; ++dt)
#pragma unroll
        for (int r = 0; r < 16; ++r) oacc[dt][r] = 0.f;

    float ls[4] = {0.f, 0.f, 0.f, 0.f};

    // K fragment: kf[hh*4+ss] = K[t*64 + hh*32 + c][ss*16 + hi*8 .. +7]
#define LOADK(dst, t_) {                                                      \
    _Pragma("unroll")                                                         \
    for (int hh_ = 0; hh_ < 2; ++hh_)                                         \
        _Pragma("unroll")                                                     \
        for (int ss_ = 0; ss_ < 4; ++ss_)                                     \
            dst[hh_ * 4 + ss_] = *(const short8*)(                            \
                Kl + ((size_t)(t_) * 64 + hh_ * 32) * 64 + ss_ * 16); }

    // V fragment: vf[dt*4+ss] = Vt[dt*32 + c][t*64 + ss*16 + hi*8 .. +7]
#define LOADV(dst, t_) {                                                      \
    _Pragma("unroll")                                                         \
    for (int dt_ = 0; dt_ < 2; ++dt_)                                         \
        _Pragma("unroll")                                                     \
        for (int ss_ = 0; ss_ < 4; ++ss_)                                     \
            dst[dt_ * 4 + ss_] = *(const short8*)(                            \
                Vl + (size_t)dt_ * 32 * SS + (t_) * 64 + ss_ * 16); }

#define BODY(t_, KCUR, KNXT) {                                                \
    const int tn_ = ((t_) + 1 < 32) ? (t_) + 1 : 31;                          \
    LOADK(KNXT, tn_);                                                         \
    short8 vf[8];                                                             \
    LOADV(vf, t_);                                                            \
    _Pragma("unroll")                                                         \
    for (int hh = 0; hh < 2; ++hh) {                                          \
        f32x4 mqh[4];                                                         \
        _Pragma("unroll")                                                     \
        for (int tt = 0; tt < 4; ++tt)                                        \
            mqh[tt] = *(const f32x4*)(maskp + (t_) * 64 + (hh * 4 + tt) * 8 + hi * 4); \
        f32x16 s4h;                                                           \
        _Pragma("unroll")                                                     \
        for (int r = 0; r < 16; ++r) s4h[r] = 0.f;                            \
        __builtin_amdgcn_s_setprio(1);                                        \
        _Pragma("unroll")                                                     \
        for (int ss = 0; ss < 4; ++ss)                                        \
            s4h = __builtin_amdgcn_mfma_f32_32x32x16_bf16(                    \
                KCUR[hh * 4 + ss], qf[ss], s4h, 0, 0, 0);                     \
        __builtin_amdgcn_s_setprio(0);                                        \
        float pvv[16];                                                        \
        _Pragma("unroll")                                                     \
        for (int r = 0; r < 16; ++r) {                                        \
            const float p = exp2fast(s4h[r] + mqh[r >> 2][r & 3]);            \
            pvv[r] = p;                                                       \
            ls[r & 3] += p;                                                   \
        }                                                                     \
        unsigned wdh[8];                                                      \
        _Pragma("unroll")                                                     \
        for (int j = 0; j < 8; ++j) wdh[j] = pk2a(pvv[2 * j], pvv[2 * j + 1]); \
        _Pragma("unroll")                                                     \
        for (int g4 = 0; g4 < 2; ++g4) {                                      \
            asm volatile("v_permlane32_swap_b32 %0, %1"                       \
                         : "+v"(wdh[4 * g4 + 0]), "+v"(wdh[4 * g4 + 2]));     \
            asm volatile("v_permlane32_swap_b32 %0, %1"                       \
                         : "+v"(wdh[4 * g4 + 1]), "+v"(wdh[4 * g4 + 3]));     \
        }                                                                     \
        __builtin_amdgcn_s_setprio(1);                                        \
        _Pragma("unroll")                                                     \
        for (int s2 = 0; s2 < 2; ++s2) {                                      \
            const int ss = hh * 2 + s2;                                       \
            union { unsigned u[4]; short8 s8; } pa;                           \
            _Pragma("unroll")                                                 \
            for (int u_ = 0; u_ < 4; ++u_) pa.u[u_] = wdh[4 * s2 + u_];       \
            _Pragma("unroll")                                                 \
            for (int dt = 0; dt < 2; ++dt)                                    \
                oacc[dt] = __builtin_amdgcn_mfma_f32_32x32x16_bf16(           \
                    pa.s8, vf[dt * 4 + ss], oacc[dt], 0, 0, 0);               \
        }                                                                     \
        __builtin_amdgcn_s_setprio(0);                                        \
    } }

    short8 kfA[8], kfB[8];
    LOADK(kfA, 0);

    for (int t = 0; t < 32; t += 2) {
        BODY(t, kfA, kfB);
        BODY(t + 1, kfB, kfA);
    }
#undef BODY
#undef LOADK
#undef LOADV

    // ---- epilogue: per-wave l reduce + broadcast to D-row layout ----
    float lsum = (ls[0] + ls[1]) + (ls[2] + ls[3]);
    lsum += __shfl_xor(lsum, 32, 64);

    Sc[wq][c] = lsum;
    asm volatile("s_waitcnt lgkmcnt(0)" ::: "memory");
    f32x4 lq[4];
#pragma unroll
    for (int tt = 0; tt < 4; ++tt)
        lq[tt] = *(const f32x4*)&Sc[wq][tt * 8 + hi * 4];

#pragma unroll
    for (int dt = 0; dt < 2; ++dt)
#pragma unroll
        for (int r = 0; r < 16; ++r) {
            const int row = (r & 3) + 8 * (r >> 2) + 4 * hi;
            const float val = oacc[dt][r] / lq[r >> 2][r & 3];
            ctx[((size_t)(b * SS + q0 + row)) * HH + h * 64 + dt * 32 + c] = f2b(val);
        }
}

// ---------------------------------------------------------------------------
extern "C" void kernel_launch(void* const* d_in, const int* in_sizes, int n_in,
                              void* d_out, int out_size, void* d_ws, size_t ws_size,
                              hipStream_t stream)
{
    const float* hs   = (const float*)d_in[0];
    const float* mask = (const float*)d_in[1];
    const float* Wq   = (const float*)d_in[2];
    const float* bq   = (const float*)d_in[3];
    const float* Wk   = (const float*)d_in[4];
    const float* bk   = (const float*)d_in[5];
    const float* Wv   = (const float*)d_in[6];
    const float* bv   = (const float*)d_in[7];
    const float* Wo   = (const float*)d_in[8];
    const float* bo   = (const float*)d_in[9];
    float* out = (float*)d_out;

    unsigned short* Ab   = (unsigned short*)d_ws;
    unsigned short* Wt   = Ab + (size_t)NTOK * HH;
    unsigned short* Qh   = Wt + (size_t)4 * HH * HH;   // Qh|Kh|Vh contiguous
    unsigned short* Kh   = Qh + (size_t)NTOK * HH;
    unsigned short* Vh   = Kh + (size_t)NTOK * HH;
    unsigned short* Vt   = Vh + (size_t)NTOK * HH;
    unsigned short* ctxb = Vt + (size_t)NTOK * HH;
    float* mbuf = (float*)(ctxb + (size_t)NTOK * HH);

    dim3 blk(256);

    cvt_hs<<<dim3(NTOK * HH / (8 * 256)), blk, 0, stream>>>(hs, Ab);
    prep_mask<<<dim3(NB * SS / 256), blk, 0, stream>>>(mask, mbuf);
    transpose_w<<<dim3(16, 16, 4), blk, 0, stream>>>(Wq, Wk, Wv, Wo, Wt);

    // fused QKV GEMM: N = 3072 (Q scaled), head-major outputs
    gemm_bf16<0><<<dim3(24, 32), blk, 0, stream>>>(Ab, Wt, bq, bk, bv, Qh);

    vtrans<<<dim3(SS / 64, NB * NHEAD), blk, 0, stream>>>(Vh, Vt);

    attn_mfma<<<dim3(512), blk, 0, stream>>>(Qh, Kh, Vt, mbuf, ctxb);

    gemm_bf16<2><<<dim3(8, 32), blk, 0, stream>>>(ctxb, Wt + 3 * (size_t)HH * HH,
                                                  bo, bo, bo, out);
}

// Round 10
// 121.026 us; speedup vs baseline: 1.8370x; 1.8370x over previous
//
#include <hip/hip_runtime.h>
#include <hip/hip_bf16.h>
#include <math.h>

#define NB 2
#define SS 2048
#define HH 1024
#define NHEAD 16
#define HDIM 64
#define NTOK (NB * SS)  // 4096

#define QSCALE 0.18033688011112042f   // 0.125 * log2(e)

typedef __attribute__((ext_vector_type(8))) short short8;
typedef __attribute__((ext_vector_type(4))) float f32x4;
typedef __attribute__((ext_vector_type(16))) float f32x16;

// byte-offset swizzle within a 128B LDS row: XOR 16B-chunk index with (row&7)
#define SWZ16(row, boff) ((boff) ^ (((row) & 7) << 4))

// f32 -> bf16 round-to-nearest-even
__device__ __forceinline__ unsigned short f2b(float x) {
    union { float f; unsigned int u; } v; v.f = x;
    unsigned int u = v.u + 0x7fff + ((v.u >> 16) & 1);
    return (unsigned short)(u >> 16);
}

// pack two f32 -> one dword of 2 bf16 via HW instruction (T12)
__device__ __forceinline__ unsigned pk2a(float lo, float hi) {
    unsigned r;
    asm("v_cvt_pk_bf16_f32 %0, %1, %2" : "=v"(r) : "v"(lo), "v"(hi));
    return r;
}

__device__ __forceinline__ float exp2fast(float x) {
#if __has_builtin(__builtin_amdgcn_exp2f)
    return __builtin_amdgcn_exp2f(x);
#else
    return exp2f(x);
#endif
}

// async global->LDS, 16B per lane
__device__ __forceinline__ void gl16(const void* g, void* l) {
    __builtin_amdgcn_global_load_lds(
        (const __attribute__((address_space(1))) void*)g,
        (__attribute__((address_space(3))) void*)l, 16, 0, 0);
}

// ---------------------------------------------------------------------------
// hs f32 -> bf16 row-major
// ---------------------------------------------------------------------------
__global__ __launch_bounds__(256) void cvt_hs(
    const float* __restrict__ X, unsigned short* __restrict__ Y)
{
    const size_t i = ((size_t)blockIdx.x * 256 + threadIdx.x) * 8;
    float4 v0 = *(const float4*)(X + i);
    float4 v1 = *(const float4*)(X + i + 4);
    short8 o;
    o[0] = f2b(v0.x); o[1] = f2b(v0.y); o[2] = f2b(v0.z); o[3] = f2b(v0.w);
    o[4] = f2b(v1.x); o[5] = f2b(v1.y); o[6] = f2b(v1.z); o[7] = f2b(v1.w);
    *(short8*)(Y + i) = o;
}

// ---------------------------------------------------------------------------
// mask compaction: per batch, deterministic prefix scan of unmasked (mask==0)
// positions -> idx list (padded with 0), count, and bias array
// (0 for j<cnt, -1e30 for pad). One block per batch, 256 threads x 8 elems.
// ---------------------------------------------------------------------------
__global__ __launch_bounds__(256) void mask_scan(
    const float* __restrict__ mask, int* __restrict__ idx,
    float* __restrict__ bias, int* __restrict__ cnt)
{
    __shared__ int part[256];
    const int b = blockIdx.x;
    const int tid = threadIdx.x;

    int loc[8]; int m = 0;
    const float* mp = mask + (size_t)b * SS + tid * 8;
#pragma unroll
    for (int j = 0; j < 8; ++j) { loc[j] = (mp[j] == 0.0f) ? 1 : 0; m += loc[j]; }
    part[tid] = m;
    __syncthreads();
    // Hillis-Steele inclusive scan
    for (int d = 1; d < 256; d <<= 1) {
        int v = (tid >= d) ? part[tid - d] : 0;
        __syncthreads();
        part[tid] += v;
        __syncthreads();
    }
    int base = part[tid] - m;          // exclusive prefix
    const int total = part[255];
#pragma unroll
    for (int j = 0; j < 8; ++j)
        if (loc[j]) idx[(size_t)b * SS + (base++)] = tid * 8 + j;
    if (tid == 0) cnt[b] = total;
    __syncthreads();
    for (int j = tid; j < SS; j += 256) {
        if (j >= total) idx[(size_t)b * SS + j] = 0;
        bias[(size_t)b * SS + j] = (j < total) ? 0.0f : -1e30f;
    }
}

// ---------------------------------------------------------------------------
// W f32 [K][N] -> Wt bf16 [N][K]  (4 weights via blockIdx.z)
// ---------------------------------------------------------------------------
__global__ __launch_bounds__(256) void transpose_w(
    const float* __restrict__ W0, const float* __restrict__ W1,
    const float* __restrict__ W2, const float* __restrict__ W3,
    unsigned short* __restrict__ Wt)
{
    const float* W = blockIdx.z == 0 ? W0 : blockIdx.z == 1 ? W1 :
                     blockIdx.z == 2 ? W2 : W3;
    unsigned short* dst = Wt + (size_t)blockIdx.z * HH * HH;
    __shared__ unsigned short T[64][72];
    const int tid = threadIdx.x;
    const int n0 = blockIdx.x * 64, k0 = blockIdx.y * 64;
    {
        const int r = tid >> 2, c4 = (tid & 3) * 16;
        const float* src = W + (size_t)(k0 + r) * HH + n0 + c4;
#pragma unroll
        for (int j = 0; j < 16; j += 4) {
            float4 v = *(const float4*)(src + j);
            T[c4 + j + 0][r] = f2b(v.x); T[c4 + j + 1][r] = f2b(v.y);
            T[c4 + j + 2][r] = f2b(v.z); T[c4 + j + 3][r] = f2b(v.w);
        }
    }
    __syncthreads();
    {
        const int n = tid >> 2, sc = (tid & 3) * 2;
#pragma unroll
        for (int u = 0; u < 2; ++u) {
            short8 v = *(const short8*)&T[n][(sc + u) * 8];
            *(short8*)(dst + (size_t)(n0 + n) * HH + k0 + (sc + u) * 8) = v;
        }
    }
}

// ---------------------------------------------------------------------------
// bf16 MFMA GEMM. OUT=0: fused QKV (N=3072): Q scaled by QSCALE, all three
// written bf16 head-major [bh][si][d]. OUT=2: f32 row-major.
// ---------------------------------------------------------------------------
template<int OUT>
__global__ __launch_bounds__(256) void gemm_bf16(
    const unsigned short* __restrict__ A, const unsigned short* __restrict__ Bt,
    const float* __restrict__ b0, const float* __restrict__ b1,
    const float* __restrict__ b2, void* __restrict__ Cout)
{
    __shared__ __align__(16) unsigned short As[2][128 * 64];
    __shared__ __align__(16) unsigned short Bs[2][128 * 64];

    const int tid = threadIdx.x;
    const int w  = tid >> 6;
    const int l  = tid & 63;
    const int g  = l >> 4, c = l & 15;
    const int wr = w >> 1, wc = w & 1;
    const int m0 = blockIdx.y * 128, n0 = blockIdx.x * 128;

    const int dr = l >> 3;
    const int gc = (l & 7) ^ dr;

    const unsigned short* aBase = A  + (size_t)(m0 + w * 32 + dr) * HH + gc * 8;
    const unsigned short* bBase = Bt + (size_t)(n0 + w * 32 + dr) * HH + gc * 8;

    f32x4 acc[4][4];
#pragma unroll
    for (int mi = 0; mi < 4; ++mi)
#pragma unroll
        for (int ni = 0; ni < 4; ++ni)
            acc[mi][ni] = (f32x4){0.f, 0.f, 0.f, 0.f};

    const int swz = (c & 7) * 8;

#define STAGE(kt_, bb) {                                                      \
    const int koff = (kt_) * 64;                                              \
    _Pragma("unroll")                                                         \
    for (int i_ = 0; i_ < 4; ++i_) {                                          \
        gl16(aBase + koff + (size_t)i_ * 8 * HH, (void*)&As[bb][(w*4+i_)*512]); \
        gl16(bBase + koff + (size_t)i_ * 8 * HH, (void*)&Bs[bb][(w*4+i_)*512]); \
    } }

    STAGE(0, 0);
    __syncthreads();
    int cur = 0;

    for (int kt = 0; kt < 16; ++kt) {
        if (kt < 15) STAGE(kt + 1, cur ^ 1);

        short8 af[2][4], bf[2][4];
#pragma unroll
        for (int ks = 0; ks < 2; ++ks) {
            const int kb = ks * 32;
#pragma unroll
            for (int mi = 0; mi < 4; ++mi) {
                const int row = wr * 64 + mi * 16 + c;
                af[ks][mi] = *(const short8*)&As[cur][row * 64 + ((kb + g * 8) ^ swz)];
            }
#pragma unroll
            for (int ni = 0; ni < 4; ++ni) {
                const int row = wc * 64 + ni * 16 + c;
                bf[ks][ni] = *(const short8*)&Bs[cur][row * 64 + ((kb + g * 8) ^ swz)];
            }
        }
        __builtin_amdgcn_s_setprio(1);
#pragma unroll
        for (int ks = 0; ks < 2; ++ks)
#pragma unroll
            for (int mi = 0; mi < 4; ++mi)
#pragma unroll
                for (int ni = 0; ni < 4; ++ni)
                    acc[mi][ni] = __builtin_amdgcn_mfma_f32_16x16x32_bf16(
                        af[ks][mi], bf[ks][ni], acc[mi][ni], 0, 0, 0);
        __builtin_amdgcn_s_setprio(0);

        __syncthreads();
        cur ^= 1;
    }
#undef STAGE

    if (OUT == 0) {
        const int which = n0 >> 10;   // block-uniform: 0=Q, 1=K, 2=V
        const float* bp = which == 0 ? b0 : which == 1 ? b1 : b2;
        const float scl = which == 0 ? QSCALE : 1.0f;
        unsigned short* dst = (unsigned short*)Cout + (size_t)which * NTOK * HH;
#pragma unroll
        for (int ni = 0; ni < 4; ++ni) {
            const int nl = (n0 + wc * 64 + ni * 16 + c) & 1023;
            const int h = nl >> 6, d = nl & 63;
            const float bv = bp[nl];
#pragma unroll
            for (int mi = 0; mi < 4; ++mi) {
                const int mBase = m0 + wr * 64 + mi * 16 + g * 4;
#pragma unroll
                for (int j = 0; j < 4; ++j) {
                    const int m = mBase + j;
                    const int b = m >> 11, si = m & 2047;
                    dst[(((size_t)(b * 16 + h)) * SS + si) * 64 + d] =
                        f2b((acc[mi][ni][j] + bv) * scl);
                }
            }
        }
    } else {
#pragma unroll
        for (int ni = 0; ni < 4; ++ni) {
            const int n = n0 + wc * 64 + ni * 16 + c;
            const float bv = b0[n];
#pragma unroll
            for (int mi = 0; mi < 4; ++mi) {
                const int mBase = m0 + wr * 64 + mi * 16 + g * 4;
#pragma unroll
                for (int j = 0; j < 4; ++j)
                    ((float*)Cout)[(size_t)(mBase + j) * HH + n] =
                        acc[mi][ni][j] + bv;
            }
        }
    }
}

// ---------------------------------------------------------------------------
// V head-major [bh][s][64] -> Vt [bh][64][j] GATHERED along unmasked idx
// ---------------------------------------------------------------------------
__global__ __launch_bounds__(256) void vtrans(
    const unsigned short* __restrict__ Vh, const int* __restrict__ idx,
    unsigned short* __restrict__ Vt)
{
    __shared__ unsigned short T[64][72];
    const int tid = threadIdx.x;
    const int bh = blockIdx.y;
    const int b  = bh >> 4;
    const int s0 = blockIdx.x * 64;
    {
        const int r = tid >> 2, dc = (tid & 3) * 16;
        const int sidx = idx[(size_t)b * SS + s0 + r];
        const unsigned short* src = Vh + ((size_t)bh * SS + sidx) * 64 + dc;
        short8 v0 = *(const short8*)src;
        short8 v1 = *(const short8*)(src + 8);
#pragma unroll
        for (int j = 0; j < 8; ++j) {
            T[dc + j][r]     = (unsigned short)v0[j];
            T[dc + 8 + j][r] = (unsigned short)v1[j];
        }
    }
    __syncthreads();
    {
        const int d = tid >> 2, sc = (tid & 3) * 2;
#pragma unroll
        for (int u = 0; u < 2; ++u) {
            short8 v = *(const short8*)&T[d][(sc + u) * 8];
            *(short8*)(Vt + ((size_t)bh * 64 + d) * SS + s0 + (sc + u) * 8) = v;
        }
    }
}

// ---------------------------------------------------------------------------
// Flash attention over COMPACTED keys (masked positions dropped; exact).
// Swapped-QK^T 32x32x16, no-max log2 softmax, 4 waves x 32q = 128 q/block.
// Reg-staged async double-buffer (T14), K gathered via idx at stage time,
// one barrier/tile. Bias add only on the single boundary tile.
// Grid 512, XCD swizzle (T1).
// ---------------------------------------------------------------------------
__global__ __launch_bounds__(256) void attn_mfma(
    const unsigned short* __restrict__ Qb, const unsigned short* __restrict__ Kb,
    const unsigned short* __restrict__ Vtb, const float* __restrict__ biasg,
    const int* __restrict__ idxg, const int* __restrict__ cntg,
    unsigned short* __restrict__ ctx)
{
    __shared__ __align__(16) unsigned short Ks[2][64 * 64];
    __shared__ __align__(16) unsigned short Vts[2][64 * 64];
    __shared__ float Sc[4][32];

    // XCD swizzle: 512 blocks, 8 XCDs -> 64-block contiguous chunks
    const int wg  = blockIdx.x;
    const int swg = (wg & 7) * 64 + (wg >> 3);
    const int qx  = swg & 15;       // 16 q-blocks of 128
    const int bh  = swg >> 4;       // 32

    const int tid = threadIdx.x;
    const int l   = tid & 63;
    const int wq  = tid >> 6;       // wave 0..3
    const int hi  = l >> 5;
    const int c   = l & 31;
    const int b   = bh >> 4, h = bh & 15;
    const int q0  = qx * 128 + wq * 32;

    const unsigned short* Qp = Qb  + (size_t)bh * SS * 64;
    const unsigned short* Kp = Kb  + (size_t)bh * SS * 64;
    const unsigned short* Vp = Vtb + (size_t)bh * 64 * SS;
    const float* biasp = biasg + (size_t)b * SS;
    const int* idxb = idxg + (size_t)b * SS;

    const int cnt    = cntg[b];
    const int nt     = (cnt + 63) >> 6;   // tiles (>=1; random mask -> ~17)
    const int ntFull = cnt >> 6;          // tiles with all-real keys (bias 0)

    // staging map: 256 threads cover 64 rows x 8 chunks, 2 rows each (K and V)
    const int sr  = tid >> 3;       // 0..31 (and +32)
    const int sc8 = tid & 7;        // 16B chunk

    // Q B-fragments (pre-scaled by QSCALE in GEMM)
    short8 qf[4];
    {
        const unsigned short* qrow = Qp + (size_t)(q0 + c) * 64 + hi * 8;
#pragma unroll
        for (int s = 0; s < 4; ++s) qf[s] = *(const short8*)(qrow + s * 16);
    }

    f32x16 oacc[2];
#pragma unroll
    for (int dt = 0; dt < 2; ++dt)
#pragma unroll
        for (int r = 0; r < 16; ++r) oacc[dt][r] = 0.f;

    float ls[4] = {0.f, 0.f, 0.f, 0.f};

    short8 kr0, kr1, vr0, vr1;   // in-flight stage registers

#define LOADREG(t_) {                                                         \
    const int* ip_ = idxb + (t_) * 64;                                        \
    const int sA_ = ip_[sr], sB_ = ip_[sr + 32];                              \
    kr0 = *(const short8*)(Kp + (size_t)sA_ * 64 + sc8 * 8);                  \
    kr1 = *(const short8*)(Kp + (size_t)sB_ * 64 + sc8 * 8);                  \
    vr0 = *(const short8*)(Vp + (size_t)sr * SS + (t_) * 64 + sc8 * 8);       \
    vr1 = *(const short8*)(Vp + (size_t)(sr + 32) * SS + (t_) * 64 + sc8 * 8); }

#define DSWRITE(bb) {                                                         \
    *(short8*)((char*)Ks[bb]  + sr * 128        + SWZ16(sr, sc8 * 16)) = kr0; \
    *(short8*)((char*)Ks[bb]  + (sr + 32) * 128 + SWZ16(sr + 32, sc8 * 16)) = kr1; \
    *(short8*)((char*)Vts[bb] + sr * 128        + SWZ16(sr, sc8 * 16)) = vr0; \
    *(short8*)((char*)Vts[bb] + (sr + 32) * 128 + SWZ16(sr + 32, sc8 * 16)) = vr1; }

    LOADREG(0);
    DSWRITE(0);
    __syncthreads();

    for (int t = 0; t < nt; ++t) {
        const int cb = t & 1;
        if (t + 1 < nt) LOADREG(t + 1);   // in flight during compute
        const bool needBias = (t >= ntFull);

#pragma unroll
        for (int hh = 0; hh < 2; ++hh) {
            // QK^T (swapped): S^T rows = k, cols = q
            f32x16 s4h;
#pragma unroll
            for (int r = 0; r < 16; ++r) s4h[r] = 0.f;
            const int krow = hh * 32 + c;
            __builtin_amdgcn_s_setprio(1);
#pragma unroll
            for (int ss = 0; ss < 4; ++ss) {
                short8 kf = *(const short8*)((char*)Ks[cb] + krow * 128 +
                                             SWZ16(krow, (ss * 2 + hi) * 16));
                s4h = __builtin_amdgcn_mfma_f32_32x32x16_bf16(kf, qf[ss], s4h, 0, 0, 0);
            }
            __builtin_amdgcn_s_setprio(0);

            // no-max softmax: real keys have bias 0 -> plain exp2;
            // only the boundary tile adds the (-1e30 pad) bias.
            float pvv[16];
            if (needBias) {
                f32x4 mqh[4];
#pragma unroll
                for (int tt = 0; tt < 4; ++tt)
                    mqh[tt] = *(const f32x4*)(biasp + t * 64 + (hh * 4 + tt) * 8 + hi * 4);
#pragma unroll
                for (int r = 0; r < 16; ++r)
                    pvv[r] = exp2fast(s4h[r] + mqh[r >> 2][r & 3]);
            } else {
#pragma unroll
                for (int r = 0; r < 16; ++r)
                    pvv[r] = exp2fast(s4h[r]);
            }
#pragma unroll
            for (int r = 0; r < 16; ++r) ls[r & 3] += pvv[r];

            // P -> bf16 A-frags: cvt_pk + permlane32_swap (T12)
            unsigned wdh[8];
#pragma unroll
            for (int j = 0; j < 8; ++j) wdh[j] = pk2a(pvv[2 * j], pvv[2 * j + 1]);
#pragma unroll
            for (int g4 = 0; g4 < 2; ++g4) {
                asm volatile("v_permlane32_swap_b32 %0, %1"
                             : "+v"(wdh[4 * g4 + 0]), "+v"(wdh[4 * g4 + 2]));
                asm volatile("v_permlane32_swap_b32 %0, %1"
                             : "+v"(wdh[4 * g4 + 1]), "+v"(wdh[4 * g4 + 3]));
            }

            // PV
            __builtin_amdgcn_s_setprio(1);
#pragma unroll
            for (int s2 = 0; s2 < 2; ++s2) {
                const int ss = hh * 2 + s2;
                union { unsigned u[4]; short8 s8; } pa;
#pragma unroll
                for (int u_ = 0; u_ < 4; ++u_) pa.u[u_] = wdh[4 * s2 + u_];
#pragma unroll
                for (int dt = 0; dt < 2; ++dt) {
                    const int vrow = dt * 32 + c;
                    short8 vf = *(const short8*)((char*)Vts[cb] + vrow * 128 +
                                                 SWZ16(vrow, (ss * 2 + hi) * 16));
                    oacc[dt] = __builtin_amdgcn_mfma_f32_32x32x16_bf16(pa.s8, vf, oacc[dt], 0, 0, 0);
                }
            }
            __builtin_amdgcn_s_setprio(0);
        }

        if (t + 1 < nt) DSWRITE(cb ^ 1);   // buffer not being read this iter
        __syncthreads();                   // writes visible; all reads of cb done
    }
#undef LOADREG
#undef DSWRITE

    // ---- epilogue: per-wave l reduce + broadcast to D-row layout ----
    float lsum = (ls[0] + ls[1]) + (ls[2] + ls[3]);
    lsum += __shfl_xor(lsum, 32, 64);

    Sc[wq][c] = lsum;
    asm volatile("s_waitcnt lgkmcnt(0)" ::: "memory");
    f32x4 lq[4];
#pragma unroll
    for (int tt = 0; tt < 4; ++tt)
        lq[tt] = *(const f32x4*)&Sc[wq][tt * 8 + hi * 4];

#pragma unroll
    for (int dt = 0; dt < 2; ++dt)
#pragma unroll
        for (int r = 0; r < 16; ++r) {
            const int row = (r & 3) + 8 * (r >> 2) + 4 * hi;
            const float val = oacc[dt][r] / lq[r >> 2][r & 3];
            ctx[((size_t)(b * SS + q0 + row)) * HH + h * 64 + dt * 32 + c] = f2b(val);
        }
}

// ---------------------------------------------------------------------------
extern "C" void kernel_launch(void* const* d_in, const int* in_sizes, int n_in,
                              void* d_out, int out_size, void* d_ws, size_t ws_size,
                              hipStream_t stream)
{
    const float* hs   = (const float*)d_in[0];
    const float* mask = (const float*)d_in[1];
    const float* Wq   = (const float*)d_in[2];
    const float* bq   = (const float*)d_in[3];
    const float* Wk   = (const float*)d_in[4];
    const float* bk   = (const float*)d_in[5];
    const float* Wv   = (const float*)d_in[6];
    const float* bv   = (const float*)d_in[7];
    const float* Wo   = (const float*)d_in[8];
    const float* bo   = (const float*)d_in[9];
    float* out = (float*)d_out;

    unsigned short* Ab   = (unsigned short*)d_ws;
    unsigned short* Wt   = Ab + (size_t)NTOK * HH;
    unsigned short* Qh   = Wt + (size_t)4 * HH * HH;   // Qh|Kh|Vh contiguous
    unsigned short* Kh   = Qh + (size_t)NTOK * HH;
    unsigned short* Vh   = Kh + (size_t)NTOK * HH;
    unsigned short* Vt   = Vh + (size_t)NTOK * HH;
    unsigned short* ctxb = Vt + (size_t)NTOK * HH;
    float* biasb = (float*)(ctxb + (size_t)NTOK * HH);
    int*   idxb  = (int*)(biasb + (size_t)NB * SS);
    int*   cntb  = idxb + (size_t)NB * SS;

    dim3 blk(256);

    cvt_hs<<<dim3(NTOK * HH / (8 * 256)), blk, 0, stream>>>(hs, Ab);
    mask_scan<<<dim3(NB), blk, 0, stream>>>(mask, idxb, biasb, cntb);
    transpose_w<<<dim3(16, 16, 4), blk, 0, stream>>>(Wq, Wk, Wv, Wo, Wt);

    // fused QKV GEMM: N = 3072 (Q scaled), head-major outputs
    gemm_bf16<0><<<dim3(24, 32), blk, 0, stream>>>(Ab, Wt, bq, bk, bv, Qh);

    vtrans<<<dim3(SS / 64, NB * NHEAD), blk, 0, stream>>>(Vh, idxb, Vt);

    attn_mfma<<<dim3(512), blk, 0, stream>>>(Qh, Kh, Vt, biasb, idxb, cntb, ctxb);

    gemm_bf16<2><<<dim3(8, 32), blk, 0, stream>>>(ctxb, Wt + 3 * (size_t)HH * HH,
                                                  bo, bo, bo, out);
}

// Round 11
// 117.485 us; speedup vs baseline: 1.8924x; 1.0301x over previous
//
#include <hip/hip_runtime.h>
#include <hip/hip_bf16.h>
#include <math.h>

#define NB 2
#define SS 2048
#define HH 1024
#define NHEAD 16
#define HDIM 64
#define NTOK (NB * SS)  // 4096

#define QSCALE 0.18033688011112042f   // 0.125 * log2(e)

typedef __attribute__((ext_vector_type(8))) short short8;
typedef __attribute__((ext_vector_type(4))) float f32x4;
typedef __attribute__((ext_vector_type(16))) float f32x16;

// byte-offset swizzle within a 128B LDS row: XOR 16B-chunk index with (row&7)
#define SWZ16(row, boff) ((boff) ^ (((row) & 7) << 4))

// f32 -> bf16 round-to-nearest-even
__device__ __forceinline__ unsigned short f2b(float x) {
    union { float f; unsigned int u; } v; v.f = x;
    unsigned int u = v.u + 0x7fff + ((v.u >> 16) & 1);
    return (unsigned short)(u >> 16);
}

// pack two f32 -> one dword of 2 bf16 via HW instruction (T12)
__device__ __forceinline__ unsigned pk2a(float lo, float hi) {
    unsigned r;
    asm("v_cvt_pk_bf16_f32 %0, %1, %2" : "=v"(r) : "v"(lo), "v"(hi));
    return r;
}

__device__ __forceinline__ float exp2fast(float x) {
#if __has_builtin(__builtin_amdgcn_exp2f)
    return __builtin_amdgcn_exp2f(x);
#else
    return exp2f(x);
#endif
}

// async global->LDS, 16B per lane
__device__ __forceinline__ void gl16(const void* g, void* l) {
    __builtin_amdgcn_global_load_lds(
        (const __attribute__((address_space(1))) void*)g,
        (__attribute__((address_space(3))) void*)l, 16, 0, 0);
}

// ---------------------------------------------------------------------------
// hs f32 -> bf16 row-major
// ---------------------------------------------------------------------------
__global__ __launch_bounds__(256) void cvt_hs(
    const float* __restrict__ X, unsigned short* __restrict__ Y)
{
    const size_t i = ((size_t)blockIdx.x * 256 + threadIdx.x) * 8;
    float4 v0 = *(const float4*)(X + i);
    float4 v1 = *(const float4*)(X + i + 4);
    short8 o;
    o[0] = f2b(v0.x); o[1] = f2b(v0.y); o[2] = f2b(v0.z); o[3] = f2b(v0.w);
    o[4] = f2b(v1.x); o[5] = f2b(v1.y); o[6] = f2b(v1.z); o[7] = f2b(v1.w);
    *(short8*)(Y + i) = o;
}

// ---------------------------------------------------------------------------
// mask compaction: per batch, deterministic prefix scan of unmasked (mask==0)
// positions -> idx list (padded with 0), count, and bias array
// (0 for j<cnt, -1e30 for pad). One block per batch, 256 threads x 8 elems.
// ---------------------------------------------------------------------------
__global__ __launch_bounds__(256) void mask_scan(
    const float* __restrict__ mask, int* __restrict__ idx,
    float* __restrict__ bias, int* __restrict__ cnt)
{
    __shared__ int part[256];
    const int b = blockIdx.x;
    const int tid = threadIdx.x;

    int loc[8]; int m = 0;
    const float* mp = mask + (size_t)b * SS + tid * 8;
#pragma unroll
    for (int j = 0; j < 8; ++j) { loc[j] = (mp[j] == 0.0f) ? 1 : 0; m += loc[j]; }
    part[tid] = m;
    __syncthreads();
    // Hillis-Steele inclusive scan
    for (int d = 1; d < 256; d <<= 1) {
        int v = (tid >= d) ? part[tid - d] : 0;
        __syncthreads();
        part[tid] += v;
        __syncthreads();
    }
    int base = part[tid] - m;          // exclusive prefix
    const int total = part[255];
#pragma unroll
    for (int j = 0; j < 8; ++j)
        if (loc[j]) idx[(size_t)b * SS + (base++)] = tid * 8 + j;
    if (tid == 0) cnt[b] = total;
    __syncthreads();
    for (int j = tid; j < SS; j += 256) {
        if (j >= total) idx[(size_t)b * SS + j] = 0;
        bias[(size_t)b * SS + j] = (j < total) ? 0.0f : -1e30f;
    }
}

// ---------------------------------------------------------------------------
// W f32 [K][N] -> Wt bf16 [N][K]  (4 weights via blockIdx.z)
// ---------------------------------------------------------------------------
__global__ __launch_bounds__(256) void transpose_w(
    const float* __restrict__ W0, const float* __restrict__ W1,
    const float* __restrict__ W2, const float* __restrict__ W3,
    unsigned short* __restrict__ Wt)
{
    const float* W = blockIdx.z == 0 ? W0 : blockIdx.z == 1 ? W1 :
                     blockIdx.z == 2 ? W2 : W3;
    unsigned short* dst = Wt + (size_t)blockIdx.z * HH * HH;
    __shared__ unsigned short T[64][72];
    const int tid = threadIdx.x;
    const int n0 = blockIdx.x * 64, k0 = blockIdx.y * 64;
    {
        const int r = tid >> 2, c4 = (tid & 3) * 16;
        const float* src = W + (size_t)(k0 + r) * HH + n0 + c4;
#pragma unroll
        for (int j = 0; j < 16; j += 4) {
            float4 v = *(const float4*)(src + j);
            T[c4 + j + 0][r] = f2b(v.x); T[c4 + j + 1][r] = f2b(v.y);
            T[c4 + j + 2][r] = f2b(v.z); T[c4 + j + 3][r] = f2b(v.w);
        }
    }
    __syncthreads();
    {
        const int n = tid >> 2, sc = (tid & 3) * 2;
#pragma unroll
        for (int u = 0; u < 2; ++u) {
            short8 v = *(const short8*)&T[n][(sc + u) * 8];
            *(short8*)(dst + (size_t)(n0 + n) * HH + k0 + (sc + u) * 8) = v;
        }
    }
}

// ---------------------------------------------------------------------------
// bf16 MFMA GEMM, m97-style SINGLE-buffered LDS (32KB -> 4 blocks/CU):
// STAGE(kt) -> barrier -> ds_read+MFMA -> barrier -> STAGE(kt+1).
// OUT=0: fused QKV (N=3072): Q scaled by QSCALE, bf16 head-major outputs.
// OUT=2: f32 row-major.
// ---------------------------------------------------------------------------
template<int OUT>
__global__ __launch_bounds__(256) void gemm_bf16(
    const unsigned short* __restrict__ A, const unsigned short* __restrict__ Bt,
    const float* __restrict__ b0, const float* __restrict__ b1,
    const float* __restrict__ b2, void* __restrict__ Cout)
{
    __shared__ __align__(16) unsigned short As[128 * 64];
    __shared__ __align__(16) unsigned short Bs[128 * 64];

    const int tid = threadIdx.x;
    const int w  = tid >> 6;
    const int l  = tid & 63;
    const int g  = l >> 4, c = l & 15;
    const int wr = w >> 1, wc = w & 1;
    const int m0 = blockIdx.y * 128, n0 = blockIdx.x * 128;

    const int dr = l >> 3;
    const int gc = (l & 7) ^ dr;

    const unsigned short* aBase = A  + (size_t)(m0 + w * 32 + dr) * HH + gc * 8;
    const unsigned short* bBase = Bt + (size_t)(n0 + w * 32 + dr) * HH + gc * 8;

    f32x4 acc[4][4];
#pragma unroll
    for (int mi = 0; mi < 4; ++mi)
#pragma unroll
        for (int ni = 0; ni < 4; ++ni)
            acc[mi][ni] = (f32x4){0.f, 0.f, 0.f, 0.f};

    const int swz = (c & 7) * 8;

#define STAGE(kt_) {                                                          \
    const int koff = (kt_) * 64;                                              \
    _Pragma("unroll")                                                         \
    for (int i_ = 0; i_ < 4; ++i_) {                                          \
        gl16(aBase + koff + (size_t)i_ * 8 * HH, (void*)&As[(w*4+i_)*512]);   \
        gl16(bBase + koff + (size_t)i_ * 8 * HH, (void*)&Bs[(w*4+i_)*512]);   \
    } }

    STAGE(0);

    for (int kt = 0; kt < 16; ++kt) {
        __syncthreads();   // staged tile visible (drains vmcnt)

        short8 af[2][4], bf[2][4];
#pragma unroll
        for (int ks = 0; ks < 2; ++ks) {
            const int kb = ks * 32;
#pragma unroll
            for (int mi = 0; mi < 4; ++mi) {
                const int row = wr * 64 + mi * 16 + c;
                af[ks][mi] = *(const short8*)&As[row * 64 + ((kb + g * 8) ^ swz)];
            }
#pragma unroll
            for (int ni = 0; ni < 4; ++ni) {
                const int row = wc * 64 + ni * 16 + c;
                bf[ks][ni] = *(const short8*)&Bs[row * 64 + ((kb + g * 8) ^ swz)];
            }
        }
        __builtin_amdgcn_s_setprio(1);
#pragma unroll
        for (int ks = 0; ks < 2; ++ks)
#pragma unroll
            for (int mi = 0; mi < 4; ++mi)
#pragma unroll
                for (int ni = 0; ni < 4; ++ni)
                    acc[mi][ni] = __builtin_amdgcn_mfma_f32_16x16x32_bf16(
                        af[ks][mi], bf[ks][ni], acc[mi][ni], 0, 0, 0);
        __builtin_amdgcn_s_setprio(0);

        __syncthreads();   // all reads done before next stage overwrites
        if (kt < 15) STAGE(kt + 1);
    }
#undef STAGE

    if (OUT == 0) {
        const int which = n0 >> 10;   // block-uniform: 0=Q, 1=K, 2=V
        const float* bp = which == 0 ? b0 : which == 1 ? b1 : b2;
        const float scl = which == 0 ? QSCALE : 1.0f;
        unsigned short* dst = (unsigned short*)Cout + (size_t)which * NTOK * HH;
#pragma unroll
        for (int ni = 0; ni < 4; ++ni) {
            const int nl = (n0 + wc * 64 + ni * 16 + c) & 1023;
            const int h = nl >> 6, d = nl & 63;
            const float bv = bp[nl];
#pragma unroll
            for (int mi = 0; mi < 4; ++mi) {
                const int mBase = m0 + wr * 64 + mi * 16 + g * 4;
#pragma unroll
                for (int j = 0; j < 4; ++j) {
                    const int m = mBase + j;
                    const int b = m >> 11, si = m & 2047;
                    dst[(((size_t)(b * 16 + h)) * SS + si) * 64 + d] =
                        f2b((acc[mi][ni][j] + bv) * scl);
                }
            }
        }
    } else {
#pragma unroll
        for (int ni = 0; ni < 4; ++ni) {
            const int n = n0 + wc * 64 + ni * 16 + c;
            const float bv = b0[n];
#pragma unroll
            for (int mi = 0; mi < 4; ++mi) {
                const int mBase = m0 + wr * 64 + mi * 16 + g * 4;
#pragma unroll
                for (int j = 0; j < 4; ++j)
                    ((float*)Cout)[(size_t)(mBase + j) * HH + n] =
                        acc[mi][ni][j] + bv;
            }
        }
    }
}

// ---------------------------------------------------------------------------
// V head-major [bh][s][64] -> Vt [bh][64][j] GATHERED along unmasked idx
// ---------------------------------------------------------------------------
__global__ __launch_bounds__(256) void vtrans(
    const unsigned short* __restrict__ Vh, const int* __restrict__ idx,
    unsigned short* __restrict__ Vt)
{
    __shared__ unsigned short T[64][72];
    const int tid = threadIdx.x;
    const int bh = blockIdx.y;
    const int b  = bh >> 4;
    const int s0 = blockIdx.x * 64;
    {
        const int r = tid >> 2, dc = (tid & 3) * 16;
        const int sidx = idx[(size_t)b * SS + s0 + r];
        const unsigned short* src = Vh + ((size_t)bh * SS + sidx) * 64 + dc;
        short8 v0 = *(const short8*)src;
        short8 v1 = *(const short8*)(src + 8);
#pragma unroll
        for (int j = 0; j < 8; ++j) {
            T[dc + j][r]     = (unsigned short)v0[j];
            T[dc + 8 + j][r] = (unsigned short)v1[j];
        }
    }
    __syncthreads();
    {
        const int d = tid >> 2, sc = (tid & 3) * 2;
#pragma unroll
        for (int u = 0; u < 2; ++u) {
            short8 v = *(const short8*)&T[d][(sc + u) * 8];
            *(short8*)(Vt + ((size_t)bh * 64 + d) * SS + s0 + (sc + u) * 8) = v;
        }
    }
}

// ---------------------------------------------------------------------------
// Flash attention over COMPACTED keys (masked positions dropped; exact).
// Swapped-QK^T 32x32x16, no-max log2 softmax, 4 waves x 32q = 128 q/block.
// Reg-staged async double-buffer (T14), K gathered via idx at stage time,
// one barrier/tile. Bias add only on the single boundary tile.
// Grid 512, XCD swizzle (T1).
// ---------------------------------------------------------------------------
__global__ __launch_bounds__(256) void attn_mfma(
    const unsigned short* __restrict__ Qb, const unsigned short* __restrict__ Kb,
    const unsigned short* __restrict__ Vtb, const float* __restrict__ biasg,
    const int* __restrict__ idxg, const int* __restrict__ cntg,
    unsigned short* __restrict__ ctx)
{
    __shared__ __align__(16) unsigned short Ks[2][64 * 64];
    __shared__ __align__(16) unsigned short Vts[2][64 * 64];
    __shared__ float Sc[4][32];

    // XCD swizzle: 512 blocks, 8 XCDs -> 64-block contiguous chunks
    const int wg  = blockIdx.x;
    const int swg = (wg & 7) * 64 + (wg >> 3);
    const int qx  = swg & 15;       // 16 q-blocks of 128
    const int bh  = swg >> 4;       // 32

    const int tid = threadIdx.x;
    const int l   = tid & 63;
    const int wq  = tid >> 6;       // wave 0..3
    const int hi  = l >> 5;
    const int c   = l & 31;
    const int b   = bh >> 4, h = bh & 15;
    const int q0  = qx * 128 + wq * 32;

    const unsigned short* Qp = Qb  + (size_t)bh * SS * 64;
    const unsigned short* Kp = Kb  + (size_t)bh * SS * 64;
    const unsigned short* Vp = Vtb + (size_t)bh * 64 * SS;
    const float* biasp = biasg + (size_t)b * SS;
    const int* idxb = idxg + (size_t)b * SS;

    const int cnt    = cntg[b];
    const int nt     = (cnt + 63) >> 6;   // tiles (>=1; random mask -> ~17)
    const int ntFull = cnt >> 6;          // tiles with all-real keys (bias 0)

    // staging map: 256 threads cover 64 rows x 8 chunks, 2 rows each (K and V)
    const int sr  = tid >> 3;       // 0..31 (and +32)
    const int sc8 = tid & 7;        // 16B chunk

    // Q B-fragments (pre-scaled by QSCALE in GEMM)
    short8 qf[4];
    {
        const unsigned short* qrow = Qp + (size_t)(q0 + c) * 64 + hi * 8;
#pragma unroll
        for (int s = 0; s < 4; ++s) qf[s] = *(const short8*)(qrow + s * 16);
    }

    f32x16 oacc[2];
#pragma unroll
    for (int dt = 0; dt < 2; ++dt)
#pragma unroll
        for (int r = 0; r < 16; ++r) oacc[dt][r] = 0.f;

    float ls[4] = {0.f, 0.f, 0.f, 0.f};

    short8 kr0, kr1, vr0, vr1;   // in-flight stage registers

#define LOADREG(t_) {                                                         \
    const int* ip_ = idxb + (t_) * 64;                                        \
    const int sA_ = ip_[sr], sB_ = ip_[sr + 32];                              \
    kr0 = *(const short8*)(Kp + (size_t)sA_ * 64 + sc8 * 8);                  \
    kr1 = *(const short8*)(Kp + (size_t)sB_ * 64 + sc8 * 8);                  \
    vr0 = *(const short8*)(Vp + (size_t)sr * SS + (t_) * 64 + sc8 * 8);       \
    vr1 = *(const short8*)(Vp + (size_t)(sr + 32) * SS + (t_) * 64 + sc8 * 8); }

#define DSWRITE(bb) {                                                         \
    *(short8*)((char*)Ks[bb]  + sr * 128        + SWZ16(sr, sc8 * 16)) = kr0; \
    *(short8*)((char*)Ks[bb]  + (sr + 32) * 128 + SWZ16(sr + 32, sc8 * 16)) = kr1; \
    *(short8*)((char*)Vts[bb] + sr * 128        + SWZ16(sr, sc8 * 16)) = vr0; \
    *(short8*)((char*)Vts[bb] + (sr + 32) * 128 + SWZ16(sr + 32, sc8 * 16)) = vr1; }

    LOADREG(0);
    DSWRITE(0);
    __syncthreads();

    for (int t = 0; t < nt; ++t) {
        const int cb = t & 1;
        if (t + 1 < nt) LOADREG(t + 1);   // in flight during compute
        const bool needBias = (t >= ntFull);

#pragma unroll
        for (int hh = 0; hh < 2; ++hh) {
            // QK^T (swapped): S^T rows = k, cols = q
            f32x16 s4h;
#pragma unroll
            for (int r = 0; r < 16; ++r) s4h[r] = 0.f;
            const int krow = hh * 32 + c;
            __builtin_amdgcn_s_setprio(1);
#pragma unroll
            for (int ss = 0; ss < 4; ++ss) {
                short8 kf = *(const short8*)((char*)Ks[cb] + krow * 128 +
                                             SWZ16(krow, (ss * 2 + hi) * 16));
                s4h = __builtin_amdgcn_mfma_f32_32x32x16_bf16(kf, qf[ss], s4h, 0, 0, 0);
            }
            __builtin_amdgcn_s_setprio(0);

            // no-max softmax: real keys have bias 0 -> plain exp2;
            // only the boundary tile adds the (-1e30 pad) bias.
            float pvv[16];
            if (needBias) {
                f32x4 mqh[4];
#pragma unroll
                for (int tt = 0; tt < 4; ++tt)
                    mqh[tt] = *(const f32x4*)(biasp + t * 64 + (hh * 4 + tt) * 8 + hi * 4);
#pragma unroll
                for (int r = 0; r < 16; ++r)
                    pvv[r] = exp2fast(s4h[r] + mqh[r >> 2][r & 3]);
            } else {
#pragma unroll
                for (int r = 0; r < 16; ++r)
                    pvv[r] = exp2fast(s4h[r]);
            }
#pragma unroll
            for (int r = 0; r < 16; ++r) ls[r & 3] += pvv[r];

            // P -> bf16 A-frags: cvt_pk + permlane32_swap (T12)
            unsigned wdh[8];
#pragma unroll
            for (int j = 0; j < 8; ++j) wdh[j] = pk2a(pvv[2 * j], pvv[2 * j + 1]);
#pragma unroll
            for (int g4 = 0; g4 < 2; ++g4) {
                asm volatile("v_permlane32_swap_b32 %0, %1"
                             : "+v"(wdh[4 * g4 + 0]), "+v"(wdh[4 * g4 + 2]));
                asm volatile("v_permlane32_swap_b32 %0, %1"
                             : "+v"(wdh[4 * g4 + 1]), "+v"(wdh[4 * g4 + 3]));
            }

            // PV
            __builtin_amdgcn_s_setprio(1);
#pragma unroll
            for (int s2 = 0; s2 < 2; ++s2) {
                const int ss = hh * 2 + s2;
                union { unsigned u[4]; short8 s8; } pa;
#pragma unroll
                for (int u_ = 0; u_ < 4; ++u_) pa.u[u_] = wdh[4 * s2 + u_];
#pragma unroll
                for (int dt = 0; dt < 2; ++dt) {
                    const int vrow = dt * 32 + c;
                    short8 vf = *(const short8*)((char*)Vts[cb] + vrow * 128 +
                                                 SWZ16(vrow, (ss * 2 + hi) * 16));
                    oacc[dt] = __builtin_amdgcn_mfma_f32_32x32x16_bf16(pa.s8, vf, oacc[dt], 0, 0, 0);
                }
            }
            __builtin_amdgcn_s_setprio(0);
        }

        if (t + 1 < nt) DSWRITE(cb ^ 1);   // buffer not being read this iter
        __syncthreads();                   // writes visible; all reads of cb done
    }
#undef LOADREG
#undef DSWRITE

    // ---- epilogue: per-wave l reduce + broadcast to D-row layout ----
    float lsum = (ls[0] + ls[1]) + (ls[2] + ls[3]);
    lsum += __shfl_xor(lsum, 32, 64);

    Sc[wq][c] = lsum;
    asm volatile("s_waitcnt lgkmcnt(0)" ::: "memory");
    f32x4 lq[4];
#pragma unroll
    for (int tt = 0; tt < 4; ++tt)
        lq[tt] = *(const f32x4*)&Sc[wq][tt * 8 + hi * 4];

#pragma unroll
    for (int dt = 0; dt < 2; ++dt)
#pragma unroll
        for (int r = 0; r < 16; ++r) {
            const int row = (r & 3) + 8 * (r >> 2) + 4 * hi;
            const float val = oacc[dt][r] / lq[r >> 2][r & 3];
            ctx[((size_t)(b * SS + q0 + row)) * HH + h * 64 + dt * 32 + c] = f2b(val);
        }
}

// ---------------------------------------------------------------------------
extern "C" void kernel_launch(void* const* d_in, const int* in_sizes, int n_in,
                              void* d_out, int out_size, void* d_ws, size_t ws_size,
                              hipStream_t stream)
{
    const float* hs   = (const float*)d_in[0];
    const float* mask = (const float*)d_in[1];
    const float* Wq   = (const float*)d_in[2];
    const float* bq   = (const float*)d_in[3];
    const float* Wk   = (const float*)d_in[4];
    const float* bk   = (const float*)d_in[5];
    const float* Wv   = (const float*)d_in[6];
    const float* bv   = (const float*)d_in[7];
    const float* Wo   = (const float*)d_in[8];
    const float* bo   = (const float*)d_in[9];
    float* out = (float*)d_out;

    unsigned short* Ab   = (unsigned short*)d_ws;
    unsigned short* Wt   = Ab + (size_t)NTOK * HH;
    unsigned short* Qh   = Wt + (size_t)4 * HH * HH;   // Qh|Kh|Vh contiguous
    unsigned short* Kh   = Qh + (size_t)NTOK * HH;
    unsigned short* Vh   = Kh + (size_t)NTOK * HH;
    unsigned short* Vt   = Vh + (size_t)NTOK * HH;
    unsigned short* ctxb = Vt + (size_t)NTOK * HH;
    float* biasb = (float*)(ctxb + (size_t)NTOK * HH);
    int*   idxb  = (int*)(biasb + (size_t)NB * SS);
    int*   cntb  = idxb + (size_t)NB * SS;

    dim3 blk(256);

    cvt_hs<<<dim3(NTOK * HH / (8 * 256)), blk, 0, stream>>>(hs, Ab);
    mask_scan<<<dim3(NB), blk, 0, stream>>>(mask, idxb, biasb, cntb);
    transpose_w<<<dim3(16, 16, 4), blk, 0, stream>>>(Wq, Wk, Wv, Wo, Wt);

    // fused QKV GEMM: N = 3072 (Q scaled), head-major outputs
    gemm_bf16<0><<<dim3(24, 32), blk, 0, stream>>>(Ab, Wt, bq, bk, bv, Qh);

    vtrans<<<dim3(SS / 64, NB * NHEAD), blk, 0, stream>>>(Vh, idxb, Vt);

    attn_mfma<<<dim3(512), blk, 0, stream>>>(Qh, Kh, Vt, biasb, idxb, cntb, ctxb);

    gemm_bf16<2><<<dim3(8, 32), blk, 0, stream>>>(ctxb, Wt + 3 * (size_t)HH * HH,
                                                  bo, bo, bo, out);
}

// Round 12
// 112.108 us; speedup vs baseline: 1.9831x; 1.0480x over previous
//
#include <hip/hip_runtime.h>
#include <hip/hip_bf16.h>
#include <math.h>

#define NB 2
#define SS 2048
#define HH 1024
#define NHEAD 16
#define HDIM 64
#define NTOK (NB * SS)  // 4096

#define QSCALE 0.18033688011112042f   // 0.125 * log2(e)

typedef __attribute__((ext_vector_type(8))) short short8;
typedef __attribute__((ext_vector_type(4))) float f32x4;
typedef __attribute__((ext_vector_type(16))) float f32x16;

// byte-offset swizzle within a 128B LDS row: XOR 16B-chunk index with (row&7)
#define SWZ16(row, boff) ((boff) ^ (((row) & 7) << 4))

// f32 -> bf16 round-to-nearest-even
__device__ __forceinline__ unsigned short f2b(float x) {
    union { float f; unsigned int u; } v; v.f = x;
    unsigned int u = v.u + 0x7fff + ((v.u >> 16) & 1);
    return (unsigned short)(u >> 16);
}

// pack two f32 -> one dword of 2 bf16 via HW instruction (T12)
__device__ __forceinline__ unsigned pk2a(float lo, float hi) {
    unsigned r;
    asm("v_cvt_pk_bf16_f32 %0, %1, %2" : "=v"(r) : "v"(lo), "v"(hi));
    return r;
}

__device__ __forceinline__ float exp2fast(float x) {
#if __has_builtin(__builtin_amdgcn_exp2f)
    return __builtin_amdgcn_exp2f(x);
#else
    return exp2f(x);
#endif
}

// async global->LDS, 16B per lane
__device__ __forceinline__ void gl16(const void* g, void* l) {
    __builtin_amdgcn_global_load_lds(
        (const __attribute__((address_space(1))) void*)g,
        (__attribute__((address_space(3))) void*)l, 16, 0, 0);
}

// ---------------------------------------------------------------------------
// hs f32 -> bf16 row-major
// ---------------------------------------------------------------------------
__global__ __launch_bounds__(256) void cvt_hs(
    const float* __restrict__ X, unsigned short* __restrict__ Y)
{
    const size_t i = ((size_t)blockIdx.x * 256 + threadIdx.x) * 8;
    float4 v0 = *(const float4*)(X + i);
    float4 v1 = *(const float4*)(X + i + 4);
    short8 o;
    o[0] = f2b(v0.x); o[1] = f2b(v0.y); o[2] = f2b(v0.z); o[3] = f2b(v0.w);
    o[4] = f2b(v1.x); o[5] = f2b(v1.y); o[6] = f2b(v1.z); o[7] = f2b(v1.w);
    *(short8*)(Y + i) = o;
}

// ---------------------------------------------------------------------------
// mask compaction: per batch, deterministic prefix scan of unmasked (mask==0)
// positions -> idx list (padded with 0), count, and bias array
// (0 for j<cnt, -1e30 for pad). One block per batch, 256 threads x 8 elems.
// ---------------------------------------------------------------------------
__global__ __launch_bounds__(256) void mask_scan(
    const float* __restrict__ mask, int* __restrict__ idx,
    float* __restrict__ bias, int* __restrict__ cnt)
{
    __shared__ int part[256];
    const int b = blockIdx.x;
    const int tid = threadIdx.x;

    int loc[8]; int m = 0;
    const float* mp = mask + (size_t)b * SS + tid * 8;
#pragma unroll
    for (int j = 0; j < 8; ++j) { loc[j] = (mp[j] == 0.0f) ? 1 : 0; m += loc[j]; }
    part[tid] = m;
    __syncthreads();
    // Hillis-Steele inclusive scan
    for (int d = 1; d < 256; d <<= 1) {
        int v = (tid >= d) ? part[tid - d] : 0;
        __syncthreads();
        part[tid] += v;
        __syncthreads();
    }
    int base = part[tid] - m;          // exclusive prefix
    const int total = part[255];
#pragma unroll
    for (int j = 0; j < 8; ++j)
        if (loc[j]) idx[(size_t)b * SS + (base++)] = tid * 8 + j;
    if (tid == 0) cnt[b] = total;
    __syncthreads();
    for (int j = tid; j < SS; j += 256) {
        if (j >= total) idx[(size_t)b * SS + j] = 0;
        bias[(size_t)b * SS + j] = (j < total) ? 0.0f : -1e30f;
    }
}

// ---------------------------------------------------------------------------
// W f32 [K][N] -> Wt bf16 [N][K]  (4 weights via blockIdx.z)
// ---------------------------------------------------------------------------
__global__ __launch_bounds__(256) void transpose_w(
    const float* __restrict__ W0, const float* __restrict__ W1,
    const float* __restrict__ W2, const float* __restrict__ W3,
    unsigned short* __restrict__ Wt)
{
    const float* W = blockIdx.z == 0 ? W0 : blockIdx.z == 1 ? W1 :
                     blockIdx.z == 2 ? W2 : W3;
    unsigned short* dst = Wt + (size_t)blockIdx.z * HH * HH;
    __shared__ unsigned short T[64][72];
    const int tid = threadIdx.x;
    const int n0 = blockIdx.x * 64, k0 = blockIdx.y * 64;
    {
        const int r = tid >> 2, c4 = (tid & 3) * 16;
        const float* src = W + (size_t)(k0 + r) * HH + n0 + c4;
#pragma unroll
        for (int j = 0; j < 16; j += 4) {
            float4 v = *(const float4*)(src + j);
            T[c4 + j + 0][r] = f2b(v.x); T[c4 + j + 1][r] = f2b(v.y);
            T[c4 + j + 2][r] = f2b(v.z); T[c4 + j + 3][r] = f2b(v.w);
        }
    }
    __syncthreads();
    {
        const int n = tid >> 2, sc = (tid & 3) * 2;
#pragma unroll
        for (int u = 0; u < 2; ++u) {
            short8 v = *(const short8*)&T[n][(sc + u) * 8];
            *(short8*)(dst + (size_t)(n0 + n) * HH + k0 + (sc + u) * 8) = v;
        }
    }
}

// ---------------------------------------------------------------------------
// bf16 MFMA GEMM, double-buffered LDS with COUNTED vmcnt (T4): loads for
// tile kt issued one full K-tile before their wait; raw s_barrier (no drain).
// OUT=0: fused QKV (N=3072): Q scaled by QSCALE, bf16 head-major outputs.
// OUT=2: f32 row-major.
// ---------------------------------------------------------------------------
template<int OUT>
__global__ __launch_bounds__(256) void gemm_bf16(
    const unsigned short* __restrict__ A, const unsigned short* __restrict__ Bt,
    const float* __restrict__ b0, const float* __restrict__ b1,
    const float* __restrict__ b2, void* __restrict__ Cout)
{
    __shared__ __align__(16) unsigned short As[2][128 * 64];
    __shared__ __align__(16) unsigned short Bs[2][128 * 64];

    const int tid = threadIdx.x;
    const int w  = tid >> 6;
    const int l  = tid & 63;
    const int g  = l >> 4, c = l & 15;
    const int wr = w >> 1, wc = w & 1;
    const int m0 = blockIdx.y * 128, n0 = blockIdx.x * 128;

    const int dr = l >> 3;
    const int gc = (l & 7) ^ dr;

    const unsigned short* aBase = A  + (size_t)(m0 + w * 32 + dr) * HH + gc * 8;
    const unsigned short* bBase = Bt + (size_t)(n0 + w * 32 + dr) * HH + gc * 8;

    f32x4 acc[4][4];
#pragma unroll
    for (int mi = 0; mi < 4; ++mi)
#pragma unroll
        for (int ni = 0; ni < 4; ++ni)
            acc[mi][ni] = (f32x4){0.f, 0.f, 0.f, 0.f};

    const int swz = (c & 7) * 8;

#define STAGE(kt_, bb) {                                                      \
    const int koff = (kt_) * 64;                                              \
    _Pragma("unroll")                                                         \
    for (int i_ = 0; i_ < 4; ++i_) {                                          \
        gl16(aBase + koff + (size_t)i_ * 8 * HH, (void*)&As[bb][(w*4+i_)*512]); \
        gl16(bBase + koff + (size_t)i_ * 8 * HH, (void*)&Bs[bb][(w*4+i_)*512]); \
    } }

    STAGE(0, 0);          //  8 loads in flight
    STAGE(1, 1);          // 16 loads in flight

    for (int kt = 0; kt < 16; ++kt) {
        const int cb = kt & 1;
        // tile kt ready: wait its 8 loads (kt+1's 8 may stay in flight)
        if (kt < 15) asm volatile("s_waitcnt vmcnt(8)" ::: "memory");
        else         asm volatile("s_waitcnt vmcnt(0)" ::: "memory");
        __builtin_amdgcn_s_barrier();            // all waves staged tile kt
        __builtin_amdgcn_sched_barrier(0);

        short8 af[2][4], bf[2][4];
#pragma unroll
        for (int ks = 0; ks < 2; ++ks) {
            const int kb = ks * 32;
#pragma unroll
            for (int mi = 0; mi < 4; ++mi) {
                const int row = wr * 64 + mi * 16 + c;
                af[ks][mi] = *(const short8*)&As[cb][row * 64 + ((kb + g * 8) ^ swz)];
            }
#pragma unroll
            for (int ni = 0; ni < 4; ++ni) {
                const int row = wc * 64 + ni * 16 + c;
                bf[ks][ni] = *(const short8*)&Bs[cb][row * 64 + ((kb + g * 8) ^ swz)];
            }
        }
        __builtin_amdgcn_s_setprio(1);
#pragma unroll
        for (int ks = 0; ks < 2; ++ks)
#pragma unroll
            for (int mi = 0; mi < 4; ++mi)
#pragma unroll
                for (int ni = 0; ni < 4; ++ni)
                    acc[mi][ni] = __builtin_amdgcn_mfma_f32_16x16x32_bf16(
                        af[ks][mi], bf[ks][ni], acc[mi][ni], 0, 0, 0);
        __builtin_amdgcn_s_setprio(0);

        __builtin_amdgcn_sched_barrier(0);
        __builtin_amdgcn_s_barrier();            // all waves done reading cb
        __builtin_amdgcn_sched_barrier(0);
        if (kt + 2 < 16) STAGE(kt + 2, cb);      // refill freed buffer
    }
#undef STAGE

    if (OUT == 0) {
        const int which = n0 >> 10;   // block-uniform: 0=Q, 1=K, 2=V
        const float* bp = which == 0 ? b0 : which == 1 ? b1 : b2;
        const float scl = which == 0 ? QSCALE : 1.0f;
        unsigned short* dst = (unsigned short*)Cout + (size_t)which * NTOK * HH;
#pragma unroll
        for (int ni = 0; ni < 4; ++ni) {
            const int nl = (n0 + wc * 64 + ni * 16 + c) & 1023;
            const int h = nl >> 6, d = nl & 63;
            const float bv = bp[nl];
#pragma unroll
            for (int mi = 0; mi < 4; ++mi) {
                const int mBase = m0 + wr * 64 + mi * 16 + g * 4;
#pragma unroll
                for (int j = 0; j < 4; ++j) {
                    const int m = mBase + j;
                    const int b = m >> 11, si = m & 2047;
                    dst[(((size_t)(b * 16 + h)) * SS + si) * 64 + d] =
                        f2b((acc[mi][ni][j] + bv) * scl);
                }
            }
        }
    } else {
#pragma unroll
        for (int ni = 0; ni < 4; ++ni) {
            const int n = n0 + wc * 64 + ni * 16 + c;
            const float bv = b0[n];
#pragma unroll
            for (int mi = 0; mi < 4; ++mi) {
                const int mBase = m0 + wr * 64 + mi * 16 + g * 4;
#pragma unroll
                for (int j = 0; j < 4; ++j)
                    ((float*)Cout)[(size_t)(mBase + j) * HH + n] =
                        acc[mi][ni][j] + bv;
            }
        }
    }
}

// ---------------------------------------------------------------------------
// V head-major [bh][s][64] -> Vt [bh][64][j] GATHERED along unmasked idx
// ---------------------------------------------------------------------------
__global__ __launch_bounds__(256) void vtrans(
    const unsigned short* __restrict__ Vh, const int* __restrict__ idx,
    unsigned short* __restrict__ Vt)
{
    __shared__ unsigned short T[64][72];
    const int tid = threadIdx.x;
    const int bh = blockIdx.y;
    const int b  = bh >> 4;
    const int s0 = blockIdx.x * 64;
    {
        const int r = tid >> 2, dc = (tid & 3) * 16;
        const int sidx = idx[(size_t)b * SS + s0 + r];
        const unsigned short* src = Vh + ((size_t)bh * SS + sidx) * 64 + dc;
        short8 v0 = *(const short8*)src;
        short8 v1 = *(const short8*)(src + 8);
#pragma unroll
        for (int j = 0; j < 8; ++j) {
            T[dc + j][r]     = (unsigned short)v0[j];
            T[dc + 8 + j][r] = (unsigned short)v1[j];
        }
    }
    __syncthreads();
    {
        const int d = tid >> 2, sc = (tid & 3) * 2;
#pragma unroll
        for (int u = 0; u < 2; ++u) {
            short8 v = *(const short8*)&T[d][(sc + u) * 8];
            *(short8*)(Vt + ((size_t)bh * 64 + d) * SS + s0 + (sc + u) * 8) = v;
        }
    }
}

// ---------------------------------------------------------------------------
// Flash attention over COMPACTED keys (masked positions dropped; exact).
// Swapped-QK^T 32x32x16, no-max log2 softmax, 4 waves x 32q = 128 q/block.
// Reg-staged async double-buffer (T14), K gathered via idx at stage time,
// one barrier/tile. Bias add only on the single boundary tile.
// Grid 512, XCD swizzle (T1).
// ---------------------------------------------------------------------------
__global__ __launch_bounds__(256) void attn_mfma(
    const unsigned short* __restrict__ Qb, const unsigned short* __restrict__ Kb,
    const unsigned short* __restrict__ Vtb, const float* __restrict__ biasg,
    const int* __restrict__ idxg, const int* __restrict__ cntg,
    unsigned short* __restrict__ ctx)
{
    __shared__ __align__(16) unsigned short Ks[2][64 * 64];
    __shared__ __align__(16) unsigned short Vts[2][64 * 64];
    __shared__ float Sc[4][32];

    // XCD swizzle: 512 blocks, 8 XCDs -> 64-block contiguous chunks
    const int wg  = blockIdx.x;
    const int swg = (wg & 7) * 64 + (wg >> 3);
    const int qx  = swg & 15;       // 16 q-blocks of 128
    const int bh  = swg >> 4;       // 32

    const int tid = threadIdx.x;
    const int l   = tid & 63;
    const int wq  = tid >> 6;       // wave 0..3
    const int hi  = l >> 5;
    const int c   = l & 31;
    const int b   = bh >> 4, h = bh & 15;
    const int q0  = qx * 128 + wq * 32;

    const unsigned short* Qp = Qb  + (size_t)bh * SS * 64;
    const unsigned short* Kp = Kb  + (size_t)bh * SS * 64;
    const unsigned short* Vp = Vtb + (size_t)bh * 64 * SS;
    const float* biasp = biasg + (size_t)b * SS;
    const int* idxb = idxg + (size_t)b * SS;

    const int cnt    = cntg[b];
    const int nt     = (cnt + 63) >> 6;   // tiles (>=1; random mask -> ~17)
    const int ntFull = cnt >> 6;          // tiles with all-real keys (bias 0)

    // staging map: 256 threads cover 64 rows x 8 chunks, 2 rows each (K and V)
    const int sr  = tid >> 3;       // 0..31 (and +32)
    const int sc8 = tid & 7;        // 16B chunk

    // Q B-fragments (pre-scaled by QSCALE in GEMM)
    short8 qf[4];
    {
        const unsigned short* qrow = Qp + (size_t)(q0 + c) * 64 + hi * 8;
#pragma unroll
        for (int s = 0; s < 4; ++s) qf[s] = *(const short8*)(qrow + s * 16);
    }

    f32x16 oacc[2];
#pragma unroll
    for (int dt = 0; dt < 2; ++dt)
#pragma unroll
        for (int r = 0; r < 16; ++r) oacc[dt][r] = 0.f;

    float ls[4] = {0.f, 0.f, 0.f, 0.f};

    short8 kr0, kr1, vr0, vr1;   // in-flight stage registers

#define LOADREG(t_) {                                                         \
    const int* ip_ = idxb + (t_) * 64;                                        \
    const int sA_ = ip_[sr], sB_ = ip_[sr + 32];                              \
    kr0 = *(const short8*)(Kp + (size_t)sA_ * 64 + sc8 * 8);                  \
    kr1 = *(const short8*)(Kp + (size_t)sB_ * 64 + sc8 * 8);                  \
    vr0 = *(const short8*)(Vp + (size_t)sr * SS + (t_) * 64 + sc8 * 8);       \
    vr1 = *(const short8*)(Vp + (size_t)(sr + 32) * SS + (t_) * 64 + sc8 * 8); }

#define DSWRITE(bb) {                                                         \
    *(short8*)((char*)Ks[bb]  + sr * 128        + SWZ16(sr, sc8 * 16)) = kr0; \
    *(short8*)((char*)Ks[bb]  + (sr + 32) * 128 + SWZ16(sr + 32, sc8 * 16)) = kr1; \
    *(short8*)((char*)Vts[bb] + sr * 128        + SWZ16(sr, sc8 * 16)) = vr0; \
    *(short8*)((char*)Vts[bb] + (sr + 32) * 128 + SWZ16(sr + 32, sc8 * 16)) = vr1; }

    LOADREG(0);
    DSWRITE(0);
    __syncthreads();

    for (int t = 0; t < nt; ++t) {
        const int cb = t & 1;
        if (t + 1 < nt) LOADREG(t + 1);   // in flight during compute
        const bool needBias = (t >= ntFull);

#pragma unroll
        for (int hh = 0; hh < 2; ++hh) {
            // QK^T (swapped): S^T rows = k, cols = q
            f32x16 s4h;
#pragma unroll
            for (int r = 0; r < 16; ++r) s4h[r] = 0.f;
            const int krow = hh * 32 + c;
            __builtin_amdgcn_s_setprio(1);
#pragma unroll
            for (int ss = 0; ss < 4; ++ss) {
                short8 kf = *(const short8*)((char*)Ks[cb] + krow * 128 +
                                             SWZ16(krow, (ss * 2 + hi) * 16));
                s4h = __builtin_amdgcn_mfma_f32_32x32x16_bf16(kf, qf[ss], s4h, 0, 0, 0);
            }
            __builtin_amdgcn_s_setprio(0);

            // no-max softmax: real keys have bias 0 -> plain exp2;
            // only the boundary tile adds the (-1e30 pad) bias.
            float pvv[16];
            if (needBias) {
                f32x4 mqh[4];
#pragma unroll
                for (int tt = 0; tt < 4; ++tt)
                    mqh[tt] = *(const f32x4*)(biasp + t * 64 + (hh * 4 + tt) * 8 + hi * 4);
#pragma unroll
                for (int r = 0; r < 16; ++r)
                    pvv[r] = exp2fast(s4h[r] + mqh[r >> 2][r & 3]);
            } else {
#pragma unroll
                for (int r = 0; r < 16; ++r)
                    pvv[r] = exp2fast(s4h[r]);
            }
#pragma unroll
            for (int r = 0; r < 16; ++r) ls[r & 3] += pvv[r];

            // P -> bf16 A-frags: cvt_pk + permlane32_swap (T12)
            unsigned wdh[8];
#pragma unroll
            for (int j = 0; j < 8; ++j) wdh[j] = pk2a(pvv[2 * j], pvv[2 * j + 1]);
#pragma unroll
            for (int g4 = 0; g4 < 2; ++g4) {
                asm volatile("v_permlane32_swap_b32 %0, %1"
                             : "+v"(wdh[4 * g4 + 0]), "+v"(wdh[4 * g4 + 2]));
                asm volatile("v_permlane32_swap_b32 %0, %1"
                             : "+v"(wdh[4 * g4 + 1]), "+v"(wdh[4 * g4 + 3]));
            }

            // PV
            __builtin_amdgcn_s_setprio(1);
#pragma unroll
            for (int s2 = 0; s2 < 2; ++s2) {
                const int ss = hh * 2 + s2;
                union { unsigned u[4]; short8 s8; } pa;
#pragma unroll
                for (int u_ = 0; u_ < 4; ++u_) pa.u[u_] = wdh[4 * s2 + u_];
#pragma unroll
                for (int dt = 0; dt < 2; ++dt) {
                    const int vrow = dt * 32 + c;
                    short8 vf = *(const short8*)((char*)Vts[cb] + vrow * 128 +
                                                 SWZ16(vrow, (ss * 2 + hi) * 16));
                    oacc[dt] = __builtin_amdgcn_mfma_f32_32x32x16_bf16(pa.s8, vf, oacc[dt], 0, 0, 0);
                }
            }
            __builtin_amdgcn_s_setprio(0);
        }

        if (t + 1 < nt) DSWRITE(cb ^ 1);   // buffer not being read this iter
        __syncthreads();                   // writes visible; all reads of cb done
    }
#undef LOADREG
#undef DSWRITE

    // ---- epilogue: per-wave l reduce + broadcast to D-row layout ----
    float lsum = (ls[0] + ls[1]) + (ls[2] + ls[3]);
    lsum += __shfl_xor(lsum, 32, 64);

    Sc[wq][c] = lsum;
    asm volatile("s_waitcnt lgkmcnt(0)" ::: "memory");
    f32x4 lq[4];
#pragma unroll
    for (int tt = 0; tt < 4; ++tt)
        lq[tt] = *(const f32x4*)&Sc[wq][tt * 8 + hi * 4];

#pragma unroll
    for (int dt = 0; dt < 2; ++dt)
#pragma unroll
        for (int r = 0; r < 16; ++r) {
            const int row = (r & 3) + 8 * (r >> 2) + 4 * hi;
            const float val = oacc[dt][r] / lq[r >> 2][r & 3];
            ctx[((size_t)(b * SS + q0 + row)) * HH + h * 64 + dt * 32 + c] = f2b(val);
        }
}

// ---------------------------------------------------------------------------
extern "C" void kernel_launch(void* const* d_in, const int* in_sizes, int n_in,
                              void* d_out, int out_size, void* d_ws, size_t ws_size,
                              hipStream_t stream)
{
    const float* hs   = (const float*)d_in[0];
    const float* mask = (const float*)d_in[1];
    const float* Wq   = (const float*)d_in[2];
    const float* bq   = (const float*)d_in[3];
    const float* Wk   = (const float*)d_in[4];
    const float* bk   = (const float*)d_in[5];
    const float* Wv   = (const float*)d_in[6];
    const float* bv   = (const float*)d_in[7];
    const float* Wo   = (const float*)d_in[8];
    const float* bo   = (const float*)d_in[9];
    float* out = (float*)d_out;

    unsigned short* Ab   = (unsigned short*)d_ws;
    unsigned short* Wt   = Ab + (size_t)NTOK * HH;
    unsigned short* Qh   = Wt + (size_t)4 * HH * HH;   // Qh|Kh|Vh contiguous
    unsigned short* Kh   = Qh + (size_t)NTOK * HH;
    unsigned short* Vh   = Kh + (size_t)NTOK * HH;
    unsigned short* Vt   = Vh + (size_t)NTOK * HH;
    unsigned short* ctxb = Vt + (size_t)NTOK * HH;
    float* biasb = (float*)(ctxb + (size_t)NTOK * HH);
    int*   idxb  = (int*)(biasb + (size_t)NB * SS);
    int*   cntb  = idxb + (size_t)NB * SS;

    dim3 blk(256);

    cvt_hs<<<dim3(NTOK * HH / (8 * 256)), blk, 0, stream>>>(hs, Ab);
    mask_scan<<<dim3(NB), blk, 0, stream>>>(mask, idxb, biasb, cntb);
    transpose_w<<<dim3(16, 16, 4), blk, 0, stream>>>(Wq, Wk, Wv, Wo, Wt);

    // fused QKV GEMM: N = 3072 (Q scaled), head-major outputs
    gemm_bf16<0><<<dim3(24, 32), blk, 0, stream>>>(Ab, Wt, bq, bk, bv, Qh);

    vtrans<<<dim3(SS / 64, NB * NHEAD), blk, 0, stream>>>(Vh, idxb, Vt);

    attn_mfma<<<dim3(512), blk, 0, stream>>>(Qh, Kh, Vt, biasb, idxb, cntb, ctxb);

    gemm_bf16<2><<<dim3(8, 32), blk, 0, stream>>>(ctxb, Wt + 3 * (size_t)HH * HH,
                                                  bo, bo, bo, out);
}

// Round 13
// 101.646 us; speedup vs baseline: 2.1872x; 1.1029x over previous
//
#include <hip/hip_runtime.h>
#include <hip/hip_bf16.h>
#include <math.h>

#define NB 2
#define SS 2048
#define HH 1024
#define NHEAD 16
#define HDIM 64
#define NTOK (NB * SS)  // 4096

#define QSCALE 0.18033688011112042f   // 0.125 * log2(e)

typedef __attribute__((ext_vector_type(8))) short short8;
typedef __attribute__((ext_vector_type(4))) float f32x4;
typedef __attribute__((ext_vector_type(16))) float f32x16;

// byte-offset swizzle within a 128B LDS row: XOR 16B-chunk index with (row&7)
#define SWZ16(row, boff) ((boff) ^ (((row) & 7) << 4))

// f32 -> bf16 round-to-nearest-even
__device__ __forceinline__ unsigned short f2b(float x) {
    union { float f; unsigned int u; } v; v.f = x;
    unsigned int u = v.u + 0x7fff + ((v.u >> 16) & 1);
    return (unsigned short)(u >> 16);
}

// pack two f32 -> one dword of 2 bf16 via HW instruction (T12)
__device__ __forceinline__ unsigned pk2a(float lo, float hi) {
    unsigned r;
    asm("v_cvt_pk_bf16_f32 %0, %1, %2" : "=v"(r) : "v"(lo), "v"(hi));
    return r;
}

__device__ __forceinline__ float exp2fast(float x) {
#if __has_builtin(__builtin_amdgcn_exp2f)
    return __builtin_amdgcn_exp2f(x);
#else
    return exp2f(x);
#endif
}

// async global->LDS, 16B per lane
__device__ __forceinline__ void gl16(const void* g, void* l) {
    __builtin_amdgcn_global_load_lds(
        (const __attribute__((address_space(1))) void*)g,
        (__attribute__((address_space(3))) void*)l, 16, 0, 0);
}

// ---------------------------------------------------------------------------
// Fused prep: blocks [0,2048) cvt_hs; [2048,3072) transpose_w; [3072,3074)
// mask_scan. All three are independent (inputs only).
// ---------------------------------------------------------------------------
__global__ __launch_bounds__(256) void prep(
    const float* __restrict__ hs,
    const float* __restrict__ mask,
    const float* __restrict__ W0, const float* __restrict__ W1,
    const float* __restrict__ W2, const float* __restrict__ W3,
    unsigned short* __restrict__ Ab,
    unsigned short* __restrict__ Wt,
    int* __restrict__ idx, float* __restrict__ bias, int* __restrict__ cnt)
{
    __shared__ unsigned short T[64][72];
    __shared__ int part[256];
    const int bid = blockIdx.x;
    const int tid = threadIdx.x;

    if (bid < 2048) {
        // ---- cvt_hs ----
        const size_t i = ((size_t)bid * 256 + tid) * 8;
        float4 v0 = *(const float4*)(hs + i);
        float4 v1 = *(const float4*)(hs + i + 4);
        short8 o;
        o[0] = f2b(v0.x); o[1] = f2b(v0.y); o[2] = f2b(v0.z); o[3] = f2b(v0.w);
        o[4] = f2b(v1.x); o[5] = f2b(v1.y); o[6] = f2b(v1.z); o[7] = f2b(v1.w);
        *(short8*)(Ab + i) = o;
    } else if (bid < 3072) {
        // ---- transpose_w ----
        const int t = bid - 2048;
        const int z = t >> 8;
        const int n0 = (t & 15) * 64, k0 = ((t >> 4) & 15) * 64;
        const float* W = z == 0 ? W0 : z == 1 ? W1 : z == 2 ? W2 : W3;
        unsigned short* dst = Wt + (size_t)z * HH * HH;
        {
            const int r = tid >> 2, c4 = (tid & 3) * 16;
            const float* src = W + (size_t)(k0 + r) * HH + n0 + c4;
#pragma unroll
            for (int j = 0; j < 16; j += 4) {
                float4 v = *(const float4*)(src + j);
                T[c4 + j + 0][r] = f2b(v.x); T[c4 + j + 1][r] = f2b(v.y);
                T[c4 + j + 2][r] = f2b(v.z); T[c4 + j + 3][r] = f2b(v.w);
            }
        }
        __syncthreads();
        {
            const int n = tid >> 2, sc = (tid & 3) * 2;
#pragma unroll
            for (int u = 0; u < 2; ++u) {
                short8 v = *(const short8*)&T[n][(sc + u) * 8];
                *(short8*)(dst + (size_t)(n0 + n) * HH + k0 + (sc + u) * 8) = v;
            }
        }
    } else {
        // ---- mask_scan ----
        const int b = bid - 3072;
        int loc[8]; int m = 0;
        const float* mp = mask + (size_t)b * SS + tid * 8;
#pragma unroll
        for (int j = 0; j < 8; ++j) { loc[j] = (mp[j] == 0.0f) ? 1 : 0; m += loc[j]; }
        part[tid] = m;
        __syncthreads();
        for (int d = 1; d < 256; d <<= 1) {
            int v = (tid >= d) ? part[tid - d] : 0;
            __syncthreads();
            part[tid] += v;
            __syncthreads();
        }
        int base = part[tid] - m;
        const int total = part[255];
#pragma unroll
        for (int j = 0; j < 8; ++j)
            if (loc[j]) idx[(size_t)b * SS + (base++)] = tid * 8 + j;
        if (tid == 0) cnt[b] = total;
        __syncthreads();
        for (int j = tid; j < SS; j += 256) {
            if (j >= total) idx[(size_t)b * SS + j] = 0;
            bias[(size_t)b * SS + j] = (j < total) ? 0.0f : -1e30f;
        }
    }
}

// ---------------------------------------------------------------------------
// QKV GEMM: BK=32 double-buffered, counted vmcnt(4), raw s_barrier.
// LDS 16KB -> 4 blocks/CU, grid 768 fully co-resident (no tail generation).
// N=3072 fused: Q scaled by QSCALE, bf16 head-major outputs.
// ---------------------------------------------------------------------------
__global__ __launch_bounds__(256) void gemm_qkv(
    const unsigned short* __restrict__ A, const unsigned short* __restrict__ Bt,
    const float* __restrict__ b0, const float* __restrict__ b1,
    const float* __restrict__ b2, unsigned short* __restrict__ Cout)
{
    __shared__ __align__(16) unsigned short As[2][128 * 32];
    __shared__ __align__(16) unsigned short Bs[2][128 * 32];

    const int tid = threadIdx.x;
    const int w  = tid >> 6;
    const int l  = tid & 63;
    const int g  = l >> 4, c = l & 15;
    const int wr = w >> 1, wc = w & 1;
    const int m0 = blockIdx.y * 128, n0 = blockIdx.x * 128;

    // staging map: per gl16 call a wave covers 16 rows x 4 chunks (64B rows)
    const int srow = l >> 2;                 // 0..15
    const int gch  = (l & 3) ^ (srow & 3);   // inverse-swizzled global chunk

    f32x4 acc[4][4];
#pragma unroll
    for (int mi = 0; mi < 4; ++mi)
#pragma unroll
        for (int ni = 0; ni < 4; ++ni)
            acc[mi][ni] = (f32x4){0.f, 0.f, 0.f, 0.f};

#define STAGE(kt_, bb) {                                                      \
    _Pragma("unroll")                                                         \
    for (int u_ = 0; u_ < 2; ++u_) {                                          \
        const int rb_ = (w * 2 + u_) * 16;                                    \
        gl16(A  + (size_t)(m0 + rb_ + srow) * HH + (kt_) * 32 + gch * 8,      \
             (void*)&As[bb][rb_ * 32]);                                       \
        gl16(Bt + (size_t)(n0 + rb_ + srow) * HH + (kt_) * 32 + gch * 8,      \
             (void*)&Bs[bb][rb_ * 32]);                                       \
    } }

    STAGE(0, 0);          // 4 loads in flight
    STAGE(1, 1);          // 8 loads in flight

    for (int kt = 0; kt < 32; ++kt) {
        const int cb = kt & 1;
        if (kt < 31) asm volatile("s_waitcnt vmcnt(4)" ::: "memory");
        else         asm volatile("s_waitcnt vmcnt(0)" ::: "memory");
        __builtin_amdgcn_s_barrier();
        __builtin_amdgcn_sched_barrier(0);

        short8 af[4], bf[4];
#pragma unroll
        for (int mi = 0; mi < 4; ++mi) {
            const int row = wr * 64 + mi * 16 + c;
            af[mi] = *(const short8*)&As[cb][row * 32 + ((g * 8) ^ ((c & 3) * 8))];
        }
#pragma unroll
        for (int ni = 0; ni < 4; ++ni) {
            const int row = wc * 64 + ni * 16 + c;
            bf[ni] = *(const short8*)&Bs[cb][row * 32 + ((g * 8) ^ ((c & 3) * 8))];
        }
        __builtin_amdgcn_s_setprio(1);
#pragma unroll
        for (int mi = 0; mi < 4; ++mi)
#pragma unroll
            for (int ni = 0; ni < 4; ++ni)
                acc[mi][ni] = __builtin_amdgcn_mfma_f32_16x16x32_bf16(
                    af[mi], bf[ni], acc[mi][ni], 0, 0, 0);
        __builtin_amdgcn_s_setprio(0);

        __builtin_amdgcn_sched_barrier(0);
        __builtin_amdgcn_s_barrier();
        __builtin_amdgcn_sched_barrier(0);
        if (kt + 2 < 32) STAGE(kt + 2, cb);
    }
#undef STAGE

    const int which = n0 >> 10;   // block-uniform: 0=Q, 1=K, 2=V
    const float* bp = which == 0 ? b0 : which == 1 ? b1 : b2;
    const float scl = which == 0 ? QSCALE : 1.0f;
    unsigned short* dst = Cout + (size_t)which * NTOK * HH;
#pragma unroll
    for (int ni = 0; ni < 4; ++ni) {
        const int nl = (n0 + wc * 64 + ni * 16 + c) & 1023;
        const int h = nl >> 6, d = nl & 63;
        const float bv = bp[nl];
#pragma unroll
        for (int mi = 0; mi < 4; ++mi) {
            const int mBase = m0 + wr * 64 + mi * 16 + g * 4;
#pragma unroll
            for (int j = 0; j < 4; ++j) {
                const int m = mBase + j;
                const int b = m >> 11, si = m & 2047;
                dst[(((size_t)(b * 16 + h)) * SS + si) * 64 + d] =
                    f2b((acc[mi][ni][j] + bv) * scl);
            }
        }
    }
}

// ---------------------------------------------------------------------------
// Out-proj GEMM (N=1024): BK=64 dbuf, counted vmcnt(8) — R12 structure.
// ---------------------------------------------------------------------------
__global__ __launch_bounds__(256) void gemm_out(
    const unsigned short* __restrict__ A, const unsigned short* __restrict__ Bt,
    const float* __restrict__ b0, float* __restrict__ Cout)
{
    __shared__ __align__(16) unsigned short As[2][128 * 64];
    __shared__ __align__(16) unsigned short Bs[2][128 * 64];

    const int tid = threadIdx.x;
    const int w  = tid >> 6;
    const int l  = tid & 63;
    const int g  = l >> 4, c = l & 15;
    const int wr = w >> 1, wc = w & 1;
    const int m0 = blockIdx.y * 128, n0 = blockIdx.x * 128;

    const int dr = l >> 3;
    const int gc = (l & 7) ^ dr;

    const unsigned short* aBase = A  + (size_t)(m0 + w * 32 + dr) * HH + gc * 8;
    const unsigned short* bBase = Bt + (size_t)(n0 + w * 32 + dr) * HH + gc * 8;

    f32x4 acc[4][4];
#pragma unroll
    for (int mi = 0; mi < 4; ++mi)
#pragma unroll
        for (int ni = 0; ni < 4; ++ni)
            acc[mi][ni] = (f32x4){0.f, 0.f, 0.f, 0.f};

    const int swz = (c & 7) * 8;

#define STAGE(kt_, bb) {                                                      \
    const int koff = (kt_) * 64;                                              \
    _Pragma("unroll")                                                         \
    for (int i_ = 0; i_ < 4; ++i_) {                                          \
        gl16(aBase + koff + (size_t)i_ * 8 * HH, (void*)&As[bb][(w*4+i_)*512]); \
        gl16(bBase + koff + (size_t)i_ * 8 * HH, (void*)&Bs[bb][(w*4+i_)*512]); \
    } }

    STAGE(0, 0);
    STAGE(1, 1);

    for (int kt = 0; kt < 16; ++kt) {
        const int cb = kt & 1;
        if (kt < 15) asm volatile("s_waitcnt vmcnt(8)" ::: "memory");
        else         asm volatile("s_waitcnt vmcnt(0)" ::: "memory");
        __builtin_amdgcn_s_barrier();
        __builtin_amdgcn_sched_barrier(0);

        short8 af[2][4], bf[2][4];
#pragma unroll
        for (int ks = 0; ks < 2; ++ks) {
            const int kb = ks * 32;
#pragma unroll
            for (int mi = 0; mi < 4; ++mi) {
                const int row = wr * 64 + mi * 16 + c;
                af[ks][mi] = *(const short8*)&As[cb][row * 64 + ((kb + g * 8) ^ swz)];
            }
#pragma unroll
            for (int ni = 0; ni < 4; ++ni) {
                const int row = wc * 64 + ni * 16 + c;
                bf[ks][ni] = *(const short8*)&Bs[cb][row * 64 + ((kb + g * 8) ^ swz)];
            }
        }
        __builtin_amdgcn_s_setprio(1);
#pragma unroll
        for (int ks = 0; ks < 2; ++ks)
#pragma unroll
            for (int mi = 0; mi < 4; ++mi)
#pragma unroll
                for (int ni = 0; ni < 4; ++ni)
                    acc[mi][ni] = __builtin_amdgcn_mfma_f32_16x16x32_bf16(
                        af[ks][mi], bf[ks][ni], acc[mi][ni], 0, 0, 0);
        __builtin_amdgcn_s_setprio(0);

        __builtin_amdgcn_sched_barrier(0);
        __builtin_amdgcn_s_barrier();
        __builtin_amdgcn_sched_barrier(0);
        if (kt + 2 < 16) STAGE(kt + 2, cb);
    }
#undef STAGE

#pragma unroll
    for (int ni = 0; ni < 4; ++ni) {
        const int n = n0 + wc * 64 + ni * 16 + c;
        const float bv = b0[n];
#pragma unroll
        for (int mi = 0; mi < 4; ++mi) {
            const int mBase = m0 + wr * 64 + mi * 16 + g * 4;
#pragma unroll
            for (int j = 0; j < 4; ++j)
                Cout[(size_t)(mBase + j) * HH + n] = acc[mi][ni][j] + bv;
        }
    }
}

// ---------------------------------------------------------------------------
// V head-major [bh][s][64] -> Vt [bh][64][j] GATHERED along unmasked idx
// ---------------------------------------------------------------------------
__global__ __launch_bounds__(256) void vtrans(
    const unsigned short* __restrict__ Vh, const int* __restrict__ idx,
    unsigned short* __restrict__ Vt)
{
    __shared__ unsigned short T[64][72];
    const int tid = threadIdx.x;
    const int bh = blockIdx.y;
    const int b  = bh >> 4;
    const int s0 = blockIdx.x * 64;
    {
        const int r = tid >> 2, dc = (tid & 3) * 16;
        const int sidx = idx[(size_t)b * SS + s0 + r];
        const unsigned short* src = Vh + ((size_t)bh * SS + sidx) * 64 + dc;
        short8 v0 = *(const short8*)src;
        short8 v1 = *(const short8*)(src + 8);
#pragma unroll
        for (int j = 0; j < 8; ++j) {
            T[dc + j][r]     = (unsigned short)v0[j];
            T[dc + 8 + j][r] = (unsigned short)v1[j];
        }
    }
    __syncthreads();
    {
        const int d = tid >> 2, sc = (tid & 3) * 2;
#pragma unroll
        for (int u = 0; u < 2; ++u) {
            short8 v = *(const short8*)&T[d][(sc + u) * 8];
            *(short8*)(Vt + ((size_t)bh * 64 + d) * SS + s0 + (sc + u) * 8) = v;
        }
    }
}

// ---------------------------------------------------------------------------
// Flash attention over COMPACTED keys (masked positions dropped; exact).
// Swapped-QK^T 32x32x16, no-max log2 softmax, 4 waves x 32q = 128 q/block.
// Reg-staged async double-buffer (T14), K gathered via idx at stage time,
// one barrier/tile. Bias add only on the boundary tile. Grid 512, XCD T1.
// ---------------------------------------------------------------------------
__global__ __launch_bounds__(256) void attn_mfma(
    const unsigned short* __restrict__ Qb, const unsigned short* __restrict__ Kb,
    const unsigned short* __restrict__ Vtb, const float* __restrict__ biasg,
    const int* __restrict__ idxg, const int* __restrict__ cntg,
    unsigned short* __restrict__ ctx)
{
    __shared__ __align__(16) unsigned short Ks[2][64 * 64];
    __shared__ __align__(16) unsigned short Vts[2][64 * 64];
    __shared__ float Sc[4][32];

    const int wg  = blockIdx.x;
    const int swg = (wg & 7) * 64 + (wg >> 3);
    const int qx  = swg & 15;
    const int bh  = swg >> 4;

    const int tid = threadIdx.x;
    const int l   = tid & 63;
    const int wq  = tid >> 6;
    const int hi  = l >> 5;
    const int c   = l & 31;
    const int b   = bh >> 4, h = bh & 15;
    const int q0  = qx * 128 + wq * 32;

    const unsigned short* Qp = Qb  + (size_t)bh * SS * 64;
    const unsigned short* Kp = Kb  + (size_t)bh * SS * 64;
    const unsigned short* Vp = Vtb + (size_t)bh * 64 * SS;
    const float* biasp = biasg + (size_t)b * SS;
    const int* idxb = idxg + (size_t)b * SS;

    const int cnt    = cntg[b];
    const int nt     = (cnt + 63) >> 6;
    const int ntFull = cnt >> 6;

    const int sr  = tid >> 3;
    const int sc8 = tid & 7;

    short8 qf[4];
    {
        const unsigned short* qrow = Qp + (size_t)(q0 + c) * 64 + hi * 8;
#pragma unroll
        for (int s = 0; s < 4; ++s) qf[s] = *(const short8*)(qrow + s * 16);
    }

    f32x16 oacc[2];
#pragma unroll
    for (int dt = 0; dt < 2; ++dt)
#pragma unroll
        for (int r = 0; r < 16; ++r) oacc[dt][r] = 0.f;

    float ls[4] = {0.f, 0.f, 0.f, 0.f};

    short8 kr0, kr1, vr0, vr1;

#define LOADREG(t_) {                                                         \
    const int* ip_ = idxb + (t_) * 64;                                        \
    const int sA_ = ip_[sr], sB_ = ip_[sr + 32];                              \
    kr0 = *(const short8*)(Kp + (size_t)sA_ * 64 + sc8 * 8);                  \
    kr1 = *(const short8*)(Kp + (size_t)sB_ * 64 + sc8 * 8);                  \
    vr0 = *(const short8*)(Vp + (size_t)sr * SS + (t_) * 64 + sc8 * 8);       \
    vr1 = *(const short8*)(Vp + (size_t)(sr + 32) * SS + (t_) * 64 + sc8 * 8); }

#define DSWRITE(bb) {                                                         \
    *(short8*)((char*)Ks[bb]  + sr * 128        + SWZ16(sr, sc8 * 16)) = kr0; \
    *(short8*)((char*)Ks[bb]  + (sr + 32) * 128 + SWZ16(sr + 32, sc8 * 16)) = kr1; \
    *(short8*)((char*)Vts[bb] + sr * 128        + SWZ16(sr, sc8 * 16)) = vr0; \
    *(short8*)((char*)Vts[bb] + (sr + 32) * 128 + SWZ16(sr + 32, sc8 * 16)) = vr1; }

    LOADREG(0);
    DSWRITE(0);
    __syncthreads();

    for (int t = 0; t < nt; ++t) {
        const int cb = t & 1;
        if (t + 1 < nt) LOADREG(t + 1);
        const bool needBias = (t >= ntFull);

#pragma unroll
        for (int hh = 0; hh < 2; ++hh) {
            f32x16 s4h;
#pragma unroll
            for (int r = 0; r < 16; ++r) s4h[r] = 0.f;
            const int krow = hh * 32 + c;
            __builtin_amdgcn_s_setprio(1);
#pragma unroll
            for (int ss = 0; ss < 4; ++ss) {
                short8 kf = *(const short8*)((char*)Ks[cb] + krow * 128 +
                                             SWZ16(krow, (ss * 2 + hi) * 16));
                s4h = __builtin_amdgcn_mfma_f32_32x32x16_bf16(kf, qf[ss], s4h, 0, 0, 0);
            }
            __builtin_amdgcn_s_setprio(0);

            float pvv[16];
            if (needBias) {
                f32x4 mqh[4];
#pragma unroll
                for (int tt = 0; tt < 4; ++tt)
                    mqh[tt] = *(const f32x4*)(biasp + t * 64 + (hh * 4 + tt) * 8 + hi * 4);
#pragma unroll
                for (int r = 0; r < 16; ++r)
                    pvv[r] = exp2fast(s4h[r] + mqh[r >> 2][r & 3]);
            } else {
#pragma unroll
                for (int r = 0; r < 16; ++r)
                    pvv[r] = exp2fast(s4h[r]);
            }
#pragma unroll
            for (int r = 0; r < 16; ++r) ls[r & 3] += pvv[r];

            unsigned wdh[8];
#pragma unroll
            for (int j = 0; j < 8; ++j) wdh[j] = pk2a(pvv[2 * j], pvv[2 * j + 1]);
#pragma unroll
            for (int g4 = 0; g4 < 2; ++g4) {
                asm volatile("v_permlane32_swap_b32 %0, %1"
                             : "+v"(wdh[4 * g4 + 0]), "+v"(wdh[4 * g4 + 2]));
                asm volatile("v_permlane32_swap_b32 %0, %1"
                             : "+v"(wdh[4 * g4 + 1]), "+v"(wdh[4 * g4 + 3]));
            }

            __builtin_amdgcn_s_setprio(1);
#pragma unroll
            for (int s2 = 0; s2 < 2; ++s2) {
                const int ss = hh * 2 + s2;
                union { unsigned u[4]; short8 s8; } pa;
#pragma unroll
                for (int u_ = 0; u_ < 4; ++u_) pa.u[u_] = wdh[4 * s2 + u_];
#pragma unroll
                for (int dt = 0; dt < 2; ++dt) {
                    const int vrow = dt * 32 + c;
                    short8 vf = *(const short8*)((char*)Vts[cb] + vrow * 128 +
                                                 SWZ16(vrow, (ss * 2 + hi) * 16));
                    oacc[dt] = __builtin_amdgcn_mfma_f32_32x32x16_bf16(pa.s8, vf, oacc[dt], 0, 0, 0);
                }
            }
            __builtin_amdgcn_s_setprio(0);
        }

        if (t + 1 < nt) DSWRITE(cb ^ 1);
        __syncthreads();
    }
#undef LOADREG
#undef DSWRITE

    float lsum = (ls[0] + ls[1]) + (ls[2] + ls[3]);
    lsum += __shfl_xor(lsum, 32, 64);

    Sc[wq][c] = lsum;
    asm volatile("s_waitcnt lgkmcnt(0)" ::: "memory");
    f32x4 lq[4];
#pragma unroll
    for (int tt = 0; tt < 4; ++tt)
        lq[tt] = *(const f32x4*)&Sc[wq][tt * 8 + hi * 4];

#pragma unroll
    for (int dt = 0; dt < 2; ++dt)
#pragma unroll
        for (int r = 0; r < 16; ++r) {
            const int row = (r & 3) + 8 * (r >> 2) + 4 * hi;
            const float val = oacc[dt][r] / lq[r >> 2][r & 3];
            ctx[((size_t)(b * SS + q0 + row)) * HH + h * 64 + dt * 32 + c] = f2b(val);
        }
}

// ---------------------------------------------------------------------------
extern "C" void kernel_launch(void* const* d_in, const int* in_sizes, int n_in,
                              void* d_out, int out_size, void* d_ws, size_t ws_size,
                              hipStream_t stream)
{
    const float* hs   = (const float*)d_in[0];
    const float* mask = (const float*)d_in[1];
    const float* Wq   = (const float*)d_in[2];
    const float* bq   = (const float*)d_in[3];
    const float* Wk   = (const float*)d_in[4];
    const float* bk   = (const float*)d_in[5];
    const float* Wv   = (const float*)d_in[6];
    const float* bv   = (const float*)d_in[7];
    const float* Wo   = (const float*)d_in[8];
    const float* bo   = (const float*)d_in[9];
    float* out = (float*)d_out;

    unsigned short* Ab   = (unsigned short*)d_ws;
    unsigned short* Wt   = Ab + (size_t)NTOK * HH;
    unsigned short* Qh   = Wt + (size_t)4 * HH * HH;   // Qh|Kh|Vh contiguous
    unsigned short* Kh   = Qh + (size_t)NTOK * HH;
    unsigned short* Vh   = Kh + (size_t)NTOK * HH;
    unsigned short* Vt   = Vh + (size_t)NTOK * HH;
    unsigned short* ctxb = Vt + (size_t)NTOK * HH;
    float* biasb = (float*)(ctxb + (size_t)NTOK * HH);
    int*   idxb  = (int*)(biasb + (size_t)NB * SS);
    int*   cntb  = idxb + (size_t)NB * SS;

    dim3 blk(256);

    prep<<<dim3(3074), blk, 0, stream>>>(hs, mask, Wq, Wk, Wv, Wo,
                                         Ab, Wt, idxb, biasb, cntb);

    gemm_qkv<<<dim3(24, 32), blk, 0, stream>>>(Ab, Wt, bq, bk, bv, Qh);

    vtrans<<<dim3(SS / 64, NB * NHEAD), blk, 0, stream>>>(Vh, idxb, Vt);

    attn_mfma<<<dim3(512), blk, 0, stream>>>(Qh, Kh, Vt, biasb, idxb, cntb, ctxb);

    gemm_out<<<dim3(8, 32), blk, 0, stream>>>(ctxb, Wt + 3 * (size_t)HH * HH,
                                              bo, out);
}